// Round 17
// baseline (412.940 us; speedup 1.0000x reference)
//
#include <hip/hip_runtime.h>
#include <hip/hip_bf16.h>
#include <math.h>

typedef short short8 __attribute__((ext_vector_type(8)));
typedef short short4v __attribute__((ext_vector_type(4)));
typedef float f32x4 __attribute__((ext_vector_type(4)));

__device__ inline void bsplit(float x, short& h, short& l) {
    __hip_bfloat16 hb = __float2bfloat16(x);
    float hf = __bfloat162float(hb);
    __hip_bfloat16 lb = __float2bfloat16(x - hf);
    h = *reinterpret_cast<short*>(&hb);
    l = *reinterpret_cast<short*>(&lb);
}

// ---------------- CSR build ----------------

__global__ void zero_i32(int* __restrict__ p, int n) {
    int i = blockIdx.x * blockDim.x + threadIdx.x;
    if (i < n) p[i] = 0;
}

__global__ void hist_kernel(const int* __restrict__ row, int* __restrict__ hist, int E) {
    int i = blockIdx.x * blockDim.x + threadIdx.x;
    if (i < E) atomicAdd(&hist[row[i]], 1);
}

// single-block scan, wave-shuffle version
__global__ void scan_kernel(const int* __restrict__ hist, int* __restrict__ rowptr,
                            int* __restrict__ cursor, int n) {
    __shared__ int wsum[16];
    __shared__ int carry_s;
    int tid = threadIdx.x, lane = tid & 63, wid = tid >> 6;
    if (tid == 0) { carry_s = 0; rowptr[0] = 0; }
    __syncthreads();
    for (int base = 0; base < n; base += 1024) {
        int idx = base + tid;
        int v = (idx < n) ? hist[idx] : 0;
        int x = v;
#pragma unroll
        for (int d = 1; d < 64; d <<= 1) {
            int t = __shfl_up(x, d, 64);
            if (lane >= d) x += t;
        }
        if (lane == 63) wsum[wid] = x;
        __syncthreads();
        if (wid == 0) {
            int s = (lane < 16) ? wsum[lane] : 0;
#pragma unroll
            for (int d = 1; d < 16; d <<= 1) {
                int t = __shfl_up(s, d, 64);
                if (lane >= d) s += t;
            }
            if (lane < 16) wsum[lane] = s;
        }
        __syncthreads();
        int woff = (wid > 0) ? wsum[wid - 1] : 0;
        int inc = x + woff + carry_s;
        if (idx < n) {
            rowptr[idx + 1] = inc;
            cursor[idx] = inc - v;
        }
        __syncthreads();
        if (tid == 1023) carry_s = inc;
        __syncthreads();
    }
}

__global__ void scatter_kernel(const int* __restrict__ row, const int* __restrict__ col,
                               const float* __restrict__ val, int* __restrict__ cursor,
                               int* __restrict__ colsort, float* __restrict__ valsort, int E) {
    int i = blockIdx.x * blockDim.x + threadIdx.x;
    if (i < E) {
        int r = row[i];
        int p = atomicAdd(&cursor[r], 1);
        colsort[p] = col[i];
        valsort[p] = val[i];
    }
}

// ---------------- dense layer GEMM: out[n,M] = A[n,K] @ W[K,M] ----------------
template <int K, int M>
__global__ void gemm_layer(const float* __restrict__ A, const float* __restrict__ W,
                           float* __restrict__ out, int n) {
    __shared__ float a[8 * K];
    int j = threadIdx.x;
    int row0 = blockIdx.x * 8;
    constexpr int K4 = K / 4;
    for (int idx = j; idx < 8 * K4; idx += M) {
        int r = idx / K4, k4 = idx % K4;
        float4 v = make_float4(0.f, 0.f, 0.f, 0.f);
        if (row0 + r < n) v = *reinterpret_cast<const float4*>(A + (long)(row0 + r) * K + k4 * 4);
        *reinterpret_cast<float4*>(a + r * K + k4 * 4) = v;
    }
    __syncthreads();
    float acc[8] = {0, 0, 0, 0, 0, 0, 0, 0};
#pragma unroll 8
    for (int k = 0; k < K; k++) {
        float w = W[k * M + j];
#pragma unroll
        for (int r = 0; r < 8; r++) acc[r] += a[r * K + k] * w;
    }
#pragma unroll
    for (int r = 0; r < 8; r++) {
        if (row0 + r < n) out[(long)(row0 + r) * M + j] = acc[r];
    }
}

// ---------------- SpMM v2 full-width: float4 gather, multi-edge per iter, prefetch ----
template <int D>
__global__ void spmm_elu_v2(const int* __restrict__ rowptr, const int* __restrict__ cols,
                            const float* __restrict__ vals, const float* __restrict__ hw,
                            float* __restrict__ out, int n) {
    constexpr int LPR = D / 4;
    constexpr int EPI = 64 / LPR;
    int wave = (blockIdx.x * blockDim.x + threadIdx.x) >> 6;
    int lane = threadIdx.x & 63;
    if (wave >= n) return;
    int sub = lane % LPR, grp = lane / LPR;
    int s = rowptr[wave], e = rowptr[wave + 1];
    float ax = 0.f, ay = 0.f, az = 0.f, aw = 0.f;
    int pe = s + grp;
    int c = 0; float v = 0.f;
    if (pe < e) { c = cols[pe]; v = vals[pe]; }
    for (int p = s; p < e; p += EPI) {
        int pn = p + EPI + grp;
        int cn = 0; float vn = 0.f;
        if (pn < e) { cn = cols[pn]; vn = vals[pn]; }
        float4 h4 = *reinterpret_cast<const float4*>(hw + (long)c * D + sub * 4);
        ax += v * h4.x; ay += v * h4.y; az += v * h4.z; aw += v * h4.w;
        c = cn; v = vn;
    }
#pragma unroll
    for (int m = LPR; m < 64; m <<= 1) {
        ax += __shfl_xor(ax, m, 64);
        ay += __shfl_xor(ay, m, 64);
        az += __shfl_xor(az, m, 64);
        aw += __shfl_xor(aw, m, 64);
    }
    if (grp == 0) {
        float4 o;
        o.x = ax > 0.f ? ax : (__expf(ax) - 1.f);
        o.y = ay > 0.f ? ay : (__expf(ay) - 1.f);
        o.z = az > 0.f ? az : (__expf(az) - 1.f);
        o.w = aw > 0.f ? aw : (__expf(aw) - 1.f);
        *reinterpret_cast<float4*>(out + (long)wave * D + sub * 4) = o;
    }
}

// ---------------- layer-3 SpMM + ELU + fused head GEMM (T = h3 @ S) ----------------
__global__ void spmm_fused3(const int* __restrict__ rowptr, const int* __restrict__ cols,
                            const float* __restrict__ vals, const float* __restrict__ hw,
                            const float* __restrict__ S,
                            short* __restrict__ Hh, short* __restrict__ Hl,
                            short* __restrict__ Th, short* __restrict__ Tl, int n) {
    constexpr int D = 64, LPR = 16, EPI = 4;
    int wave = (blockIdx.x * blockDim.x + threadIdx.x) >> 6;
    int lane = threadIdx.x & 63;
    if (wave >= n) return;
    int sub = lane % LPR, grp = lane / LPR;
    int s = rowptr[wave], e = rowptr[wave + 1];
    float ax = 0.f, ay = 0.f, az = 0.f, aw = 0.f;
    int pe = s + grp;
    int c = 0; float v = 0.f;
    if (pe < e) { c = cols[pe]; v = vals[pe]; }
    for (int p = s; p < e; p += EPI) {
        int pn = p + EPI + grp;
        int cn = 0; float vn = 0.f;
        if (pn < e) { cn = cols[pn]; vn = vals[pn]; }
        float4 h4 = *reinterpret_cast<const float4*>(hw + (long)c * D + sub * 4);
        ax += v * h4.x; ay += v * h4.y; az += v * h4.z; aw += v * h4.w;
        c = cn; v = vn;
    }
#pragma unroll
    for (int m = LPR; m < 64; m <<= 1) {
        ax += __shfl_xor(ax, m, 64);
        ay += __shfl_xor(ay, m, 64);
        az += __shfl_xor(az, m, 64);
        aw += __shfl_xor(aw, m, 64);
    }
    float4 o;
    o.x = ax > 0.f ? ax : (__expf(ax) - 1.f);
    o.y = ay > 0.f ? ay : (__expf(ay) - 1.f);
    o.z = az > 0.f ? az : (__expf(az) - 1.f);
    o.w = aw > 0.f ? aw : (__expf(aw) - 1.f);

    if (grp == 0) {
        short4v hs, ls;
        short t0, t1, t2, t3, u0, u1, u2, u3;
        bsplit(o.x, t0, u0);
        bsplit(o.y, t1, u1);
        bsplit(o.z, t2, u2);
        bsplit(o.w, t3, u3);
        hs[0] = t0; hs[1] = t1; hs[2] = t2; hs[3] = t3;
        ls[0] = u0; ls[1] = u1; ls[2] = u2; ls[3] = u3;
        *reinterpret_cast<short4v*>(Hh + (long)wave * D + sub * 4) = hs;
        *reinterpret_cast<short4v*>(Hl + (long)wave * D + sub * 4) = ls;
    }

    float t = 0.f;
#pragma unroll
    for (int k = 0; k < 64; k++) {
        float hk;
        switch (k & 3) {
            case 0: hk = __shfl(o.x, k >> 2, 64); break;
            case 1: hk = __shfl(o.y, k >> 2, 64); break;
            case 2: hk = __shfl(o.z, k >> 2, 64); break;
            default: hk = __shfl(o.w, k >> 2, 64); break;
        }
        t += hk * S[k * 64 + lane];
    }
    short th, tl;
    bsplit(t, th, tl);
    Th[(long)wave * 64 + lane] = th;
    Tl[(long)wave * 64 + lane] = tl;
}

// ---------------- S = (Wb + Wb^T)/2 ----------------
__global__ void sym_kernel(const float* __restrict__ Wb, float* __restrict__ S) {
    int i = blockIdx.x * blockDim.x + threadIdx.x;
    if (i < 64 * 64) {
        int r = i >> 6, c = i & 63;
        S[i] = 0.5f * (Wb[r * 64 + c] + Wb[c * 64 + r]);
    }
}

// ---------------- zero the padded rows of the bf16 operands ----------------
__global__ void pad_zero(short* __restrict__ Th, short* __restrict__ Tl,
                         short* __restrict__ Hh, short* __restrict__ Hl,
                         int startRow, int padRows) {
    int i = blockIdx.x * blockDim.x + threadIdx.x;
    int tot = padRows * 64;
    if (i < tot) {
        long off = (long)startRow * 64 + i;
        Th[off] = 0; Tl[off] = 0; Hh[off] = 0; Hl[off] = 0;
    }
}

// ---------------- final: out = sigmoid(T @ H^T) via split-bf16 MFMA ----------------
// R12 version (best measured): direct scattered nontemporal stores.
__global__ __launch_bounds__(256, 2) void final_mfma(
    const short* __restrict__ Th, const short* __restrict__ Tl,
    const short* __restrict__ Hh, const short* __restrict__ Hl,
    float* __restrict__ out, int n, int G, int ypx) {
    int bid = blockIdx.x;
    int xcd = bid & 7;
    int s4 = bid >> 3;
    int by = xcd * ypx + s4 % ypx;
    int bx = s4 / ypx;
    if (by >= G) return;

    int tid = threadIdx.x;
    int wave = tid >> 6, lane = tid & 63;
    int row0 = by * 128 + (wave >> 1) * 64;
    int col0 = bx * 128 + (wave & 1) * 64;
    int lrow = lane & 15;
    int koff = (lane >> 4) * 8;

    const short* ThB = Th + (long)(row0 + lrow) * 64 + koff;
    const short* TlB = Tl + (long)(row0 + lrow) * 64 + koff;
    const short* HhB = Hh + (long)(col0 + lrow) * 64 + koff;
    const short* HlB = Hl + (long)(col0 + lrow) * 64 + koff;

    f32x4 acc[4][4];
#pragma unroll
    for (int r = 0; r < 4; r++)
#pragma unroll
        for (int c = 0; c < 4; c++) acc[r][c] = (f32x4){0.f, 0.f, 0.f, 0.f};

#pragma unroll
    for (int ks = 0; ks < 2; ks++) {
        int kb = ks * 32;
        short8 ah[4], al[4];
#pragma unroll
        for (int r = 0; r < 4; r++) ah[r] = *reinterpret_cast<const short8*>(ThB + (long)(r * 16) * 64 + kb);
#pragma unroll
        for (int r = 0; r < 4; r++) al[r] = *reinterpret_cast<const short8*>(TlB + (long)(r * 16) * 64 + kb);

#pragma unroll
        for (int c = 0; c < 4; c++) {
            short8 bh = *reinterpret_cast<const short8*>(HhB + (long)(c * 16) * 64 + kb);
            short8 bl = *reinterpret_cast<const short8*>(HlB + (long)(c * 16) * 64 + kb);
#pragma unroll
            for (int r = 0; r < 4; r++)
                acc[r][c] = __builtin_amdgcn_mfma_f32_16x16x32_bf16(ah[r], bh, acc[r][c], 0, 0, 0);
#pragma unroll
            for (int r = 0; r < 4; r++)
                acc[r][c] = __builtin_amdgcn_mfma_f32_16x16x32_bf16(ah[r], bl, acc[r][c], 0, 0, 0);
#pragma unroll
            for (int r = 0; r < 4; r++)
                acc[r][c] = __builtin_amdgcn_mfma_f32_16x16x32_bf16(al[r], bh, acc[r][c], 0, 0, 0);
        }
    }

    // epilogue: C/D layout col = lane&15, row = (lane>>4)*4 + reg  [m89-verified]
    int orow = (lane >> 4) * 4;
    bool full = (row0 + 64 <= n) && (col0 + 64 <= n);
    if (full) {
#pragma unroll
        for (int r = 0; r < 4; r++) {
#pragma unroll
            for (int q = 0; q < 4; q++) {
                long base = (long)(row0 + r * 16 + orow + q) * n + col0 + lrow;
#pragma unroll
                for (int c = 0; c < 4; c++) {
                    float x = acc[r][c][q];
                    __builtin_nontemporal_store(__builtin_amdgcn_rcpf(1.f + __expf(-x)),
                                                out + base + c * 16);
                }
            }
        }
    } else {
#pragma unroll
        for (int r = 0; r < 4; r++) {
#pragma unroll
            for (int q = 0; q < 4; q++) {
                int i = row0 + r * 16 + orow + q;
                if (i < n) {
#pragma unroll
                    for (int c = 0; c < 4; c++) {
                        int j = col0 + c * 16 + lrow;
                        if (j < n) {
                            float x = acc[r][c][q];
                            __builtin_nontemporal_store(__builtin_amdgcn_rcpf(1.f + __expf(-x)),
                                                        out + (long)i * n + j);
                        }
                    }
                }
            }
        }
    }
}

// ---------------- launch ----------------
extern "C" void kernel_launch(void* const* d_in, const int* in_sizes, int n_in,
                              void* d_out, int out_size, void* d_ws, size_t ws_size,
                              hipStream_t stream) {
    const float* x    = (const float*)d_in[0];
    const int*   erow = (const int*)d_in[1];
    const int*   ecol = (const int*)d_in[2];
    const float* eval = (const float*)d_in[3];
    const float* W0   = (const float*)d_in[4];
    const float* W1   = (const float*)d_in[5];
    const float* W2   = (const float*)d_in[6];
    const float* Wb   = (const float*)d_in[7];
    float* out = (float*)d_out;

    int N = in_sizes[0] / 128;
    int E = in_sizes[1];
    int G = (N + 127) / 128;
    int Npad = G * 128;

    char* w = (char*)d_ws;
    size_t off = 0;
    auto alloc = [&](size_t bytes) -> void* {
        void* p = w + off;
        off += (bytes + 255) & ~(size_t)255;
        return p;
    };
    float* bufA    = (float*)alloc((size_t)N * 128 * 4);
    float* bufB    = (float*)alloc((size_t)N * 128 * 4);
    float* S       = (float*)alloc(64 * 64 * 4);
    int*   colsort = (int*)alloc((size_t)E * 4);
    float* valsort = (float*)alloc((size_t)E * 4);
    int*   rowptr  = (int*)alloc((size_t)(N + 1) * 4);
    int*   cursor  = (int*)alloc((size_t)N * 4);
    int*   hist    = (int*)alloc((size_t)N * 4);
    short* Th      = (short*)alloc((size_t)Npad * 64 * 2);
    short* Tl      = (short*)alloc((size_t)Npad * 64 * 2);
    short* Hh      = (short*)alloc((size_t)Npad * 64 * 2);
    short* Hl      = (short*)alloc((size_t)Npad * 64 * 2);

    // CSR build
    zero_i32<<<(N + 255) / 256, 256, 0, stream>>>(hist, N);
    hist_kernel<<<(E + 255) / 256, 256, 0, stream>>>(erow, hist, E);
    scan_kernel<<<1, 1024, 0, stream>>>(hist, rowptr, cursor, N);
    scatter_kernel<<<(E + 255) / 256, 256, 0, stream>>>(erow, ecol, eval, cursor, colsort, valsort, E);

    int gb8 = (N + 7) / 8;
    int spmmG = (N + 3) / 4;
    sym_kernel<<<16, 256, 0, stream>>>(Wb, S);
    // ABLATION (R18): each spmm launched 3x (pure functions -> idempotent).
    // Delta dur vs R15 = 2x total spmm cost.
    // layer 1
    gemm_layer<128, 128><<<gb8, 128, 0, stream>>>(x, W0, bufB, N);
    spmm_elu_v2<128><<<spmmG, 256, 0, stream>>>(rowptr, colsort, valsort, bufB, bufA, N);
    spmm_elu_v2<128><<<spmmG, 256, 0, stream>>>(rowptr, colsort, valsort, bufB, bufA, N);
    spmm_elu_v2<128><<<spmmG, 256, 0, stream>>>(rowptr, colsort, valsort, bufB, bufA, N);
    // layer 2
    gemm_layer<128, 128><<<gb8, 128, 0, stream>>>(bufA, W1, bufB, N);
    spmm_elu_v2<128><<<spmmG, 256, 0, stream>>>(rowptr, colsort, valsort, bufB, bufA, N);
    spmm_elu_v2<128><<<spmmG, 256, 0, stream>>>(rowptr, colsort, valsort, bufB, bufA, N);
    spmm_elu_v2<128><<<spmmG, 256, 0, stream>>>(rowptr, colsort, valsort, bufB, bufA, N);
    // layer 3 (128 -> 64) + fused head
    gemm_layer<128, 64><<<gb8, 64, 0, stream>>>(bufA, W2, bufB, N);
    spmm_fused3<<<spmmG, 256, 0, stream>>>(rowptr, colsort, valsort, bufB, S, Hh, Hl, Th, Tl, N);
    spmm_fused3<<<spmmG, 256, 0, stream>>>(rowptr, colsort, valsort, bufB, S, Hh, Hl, Th, Tl, N);
    spmm_fused3<<<spmmG, 256, 0, stream>>>(rowptr, colsort, valsort, bufB, S, Hh, Hl, Th, Tl, N);

    int padRows = Npad - N;
    if (padRows > 0)
        pad_zero<<<(padRows * 64 + 255) / 256, 256, 0, stream>>>(Th, Tl, Hh, Hl, N, padRows);

    int ypx = (G + 7) / 8;                 // y-tiles per XCD band
    int nwg = 8 * ypx * G;                 // padded; blocks with by>=G early-exit
    final_mfma<<<nwg, 256, 0, stream>>>(Th, Tl, Hh, Hl, out, N, G, ypx);
}

// Round 18
// 311.039 us; speedup vs baseline: 1.3276x; 1.3276x over previous
//
#include <hip/hip_runtime.h>
#include <hip/hip_bf16.h>
#include <math.h>

typedef short short8 __attribute__((ext_vector_type(8)));
typedef short short4v __attribute__((ext_vector_type(4)));
typedef float f32x4 __attribute__((ext_vector_type(4)));

__device__ inline void bsplit(float x, short& h, short& l) {
    __hip_bfloat16 hb = __float2bfloat16(x);
    float hf = __bfloat162float(hb);
    __hip_bfloat16 lb = __float2bfloat16(x - hf);
    h = *reinterpret_cast<short*>(&hb);
    l = *reinterpret_cast<short*>(&lb);
}

// ---------------- CSR build ----------------

__global__ void zero_i32(int* __restrict__ p, int n) {
    int i = blockIdx.x * blockDim.x + threadIdx.x;
    if (i < n) p[i] = 0;
}

__global__ void hist_kernel(const int* __restrict__ row, int* __restrict__ hist, int E) {
    int i = blockIdx.x * blockDim.x + threadIdx.x;
    if (i < E) atomicAdd(&hist[row[i]], 1);
}

// ---- parallel scan (3 kernels, bit-identical to serial integer scan) ----
__global__ __launch_bounds__(256) void scan_partial(const int* __restrict__ hist,
                                                    int* __restrict__ bsum, int n) {
    __shared__ int ws_[4];
    int tid = threadIdx.x, lane = tid & 63, wid = tid >> 6;
    int idx = blockIdx.x * 256 + tid;
    int x = (idx < n) ? hist[idx] : 0;
#pragma unroll
    for (int m = 1; m < 64; m <<= 1) x += __shfl_xor(x, m, 64);
    if (lane == 0) ws_[wid] = x;
    __syncthreads();
    if (tid == 0) bsum[blockIdx.x] = ws_[0] + ws_[1] + ws_[2] + ws_[3];
}

// single wave scans nb (<=64) block sums in place (inclusive)
__global__ void scan_bsums(int* __restrict__ bsum, int nb) {
    int lane = threadIdx.x & 63;
    int x = (lane < nb) ? bsum[lane] : 0;
#pragma unroll
    for (int d = 1; d < 64; d <<= 1) {
        int t = __shfl_up(x, d, 64);
        if (lane >= d) x += t;
    }
    if (lane < nb) bsum[lane] = x;
}

__global__ __launch_bounds__(256) void scan_final(const int* __restrict__ hist,
                                                  const int* __restrict__ bsum,
                                                  int* __restrict__ rowptr,
                                                  int* __restrict__ cursor, int n) {
    __shared__ int wsum[4];
    int tid = threadIdx.x, lane = tid & 63, wid = tid >> 6;
    int b = blockIdx.x;
    int idx = b * 256 + tid;
    int v = (idx < n) ? hist[idx] : 0;
    int x = v;
#pragma unroll
    for (int d = 1; d < 64; d <<= 1) {
        int t = __shfl_up(x, d, 64);
        if (lane >= d) x += t;
    }
    if (lane == 63) wsum[wid] = x;
    __syncthreads();
    int add = (b > 0) ? bsum[b - 1] : 0;
    for (int w_ = 0; w_ < wid; w_++) add += wsum[w_];
    int inc = x + add;
    if (idx < n) {
        rowptr[idx + 1] = inc;
        cursor[idx] = inc - v;
    }
    if (b == 0 && tid == 0) rowptr[0] = 0;
}

__global__ void scatter_kernel(const int* __restrict__ row, const int* __restrict__ col,
                               const float* __restrict__ val, int* __restrict__ cursor,
                               int* __restrict__ colsort, float* __restrict__ valsort, int E) {
    int i = blockIdx.x * blockDim.x + threadIdx.x;
    if (i < E) {
        int r = row[i];
        int p = atomicAdd(&cursor[r], 1);
        colsort[p] = col[i];
        valsort[p] = val[i];
    }
}

// ---------------- dense layer GEMM: out[n,M] = A[n,K] @ W[K,M] ----------------
template <int K, int M>
__global__ void gemm_layer(const float* __restrict__ A, const float* __restrict__ W,
                           float* __restrict__ out, int n) {
    __shared__ float a[8 * K];
    int j = threadIdx.x;
    int row0 = blockIdx.x * 8;
    constexpr int K4 = K / 4;
    for (int idx = j; idx < 8 * K4; idx += M) {
        int r = idx / K4, k4 = idx % K4;
        float4 v = make_float4(0.f, 0.f, 0.f, 0.f);
        if (row0 + r < n) v = *reinterpret_cast<const float4*>(A + (long)(row0 + r) * K + k4 * 4);
        *reinterpret_cast<float4*>(a + r * K + k4 * 4) = v;
    }
    __syncthreads();
    float acc[8] = {0, 0, 0, 0, 0, 0, 0, 0};
#pragma unroll 8
    for (int k = 0; k < K; k++) {
        float w = W[k * M + j];
#pragma unroll
        for (int r = 0; r < 8; r++) acc[r] += a[r * K + k] * w;
    }
#pragma unroll
    for (int r = 0; r < 8; r++) {
        if (row0 + r < n) out[(long)(row0 + r) * M + j] = acc[r];
    }
}

// ---------------- SpMM v2 full-width ----------------
template <int D>
__global__ void spmm_elu_v2(const int* __restrict__ rowptr, const int* __restrict__ cols,
                            const float* __restrict__ vals, const float* __restrict__ hw,
                            float* __restrict__ out, int n) {
    constexpr int LPR = D / 4;
    constexpr int EPI = 64 / LPR;
    int wave = (blockIdx.x * blockDim.x + threadIdx.x) >> 6;
    int lane = threadIdx.x & 63;
    if (wave >= n) return;
    int sub = lane % LPR, grp = lane / LPR;
    int s = rowptr[wave], e = rowptr[wave + 1];
    float ax = 0.f, ay = 0.f, az = 0.f, aw = 0.f;
    int pe = s + grp;
    int c = 0; float v = 0.f;
    if (pe < e) { c = cols[pe]; v = vals[pe]; }
    for (int p = s; p < e; p += EPI) {
        int pn = p + EPI + grp;
        int cn = 0; float vn = 0.f;
        if (pn < e) { cn = cols[pn]; vn = vals[pn]; }
        float4 h4 = *reinterpret_cast<const float4*>(hw + (long)c * D + sub * 4);
        ax += v * h4.x; ay += v * h4.y; az += v * h4.z; aw += v * h4.w;
        c = cn; v = vn;
    }
#pragma unroll
    for (int m = LPR; m < 64; m <<= 1) {
        ax += __shfl_xor(ax, m, 64);
        ay += __shfl_xor(ay, m, 64);
        az += __shfl_xor(az, m, 64);
        aw += __shfl_xor(aw, m, 64);
    }
    if (grp == 0) {
        float4 o;
        o.x = ax > 0.f ? ax : (__expf(ax) - 1.f);
        o.y = ay > 0.f ? ay : (__expf(ay) - 1.f);
        o.z = az > 0.f ? az : (__expf(az) - 1.f);
        o.w = aw > 0.f ? aw : (__expf(aw) - 1.f);
        *reinterpret_cast<float4*>(out + (long)wave * D + sub * 4) = o;
    }
}

// ---------------- layer-3 SpMM + ELU + fused head GEMM (T = h3 @ S) ----------------
__global__ void spmm_fused3(const int* __restrict__ rowptr, const int* __restrict__ cols,
                            const float* __restrict__ vals, const float* __restrict__ hw,
                            const float* __restrict__ S,
                            short* __restrict__ Hh, short* __restrict__ Hl,
                            short* __restrict__ Th, short* __restrict__ Tl, int n) {
    constexpr int D = 64, LPR = 16, EPI = 4;
    int wave = (blockIdx.x * blockDim.x + threadIdx.x) >> 6;
    int lane = threadIdx.x & 63;
    if (wave >= n) return;
    int sub = lane % LPR, grp = lane / LPR;
    int s = rowptr[wave], e = rowptr[wave + 1];
    float ax = 0.f, ay = 0.f, az = 0.f, aw = 0.f;
    int pe = s + grp;
    int c = 0; float v = 0.f;
    if (pe < e) { c = cols[pe]; v = vals[pe]; }
    for (int p = s; p < e; p += EPI) {
        int pn = p + EPI + grp;
        int cn = 0; float vn = 0.f;
        if (pn < e) { cn = cols[pn]; vn = vals[pn]; }
        float4 h4 = *reinterpret_cast<const float4*>(hw + (long)c * D + sub * 4);
        ax += v * h4.x; ay += v * h4.y; az += v * h4.z; aw += v * h4.w;
        c = cn; v = vn;
    }
#pragma unroll
    for (int m = LPR; m < 64; m <<= 1) {
        ax += __shfl_xor(ax, m, 64);
        ay += __shfl_xor(ay, m, 64);
        az += __shfl_xor(az, m, 64);
        aw += __shfl_xor(aw, m, 64);
    }
    float4 o;
    o.x = ax > 0.f ? ax : (__expf(ax) - 1.f);
    o.y = ay > 0.f ? ay : (__expf(ay) - 1.f);
    o.z = az > 0.f ? az : (__expf(az) - 1.f);
    o.w = aw > 0.f ? aw : (__expf(aw) - 1.f);

    if (grp == 0) {
        short4v hs, ls;
        short t0, t1, t2, t3, u0, u1, u2, u3;
        bsplit(o.x, t0, u0);
        bsplit(o.y, t1, u1);
        bsplit(o.z, t2, u2);
        bsplit(o.w, t3, u3);
        hs[0] = t0; hs[1] = t1; hs[2] = t2; hs[3] = t3;
        ls[0] = u0; ls[1] = u1; ls[2] = u2; ls[3] = u3;
        *reinterpret_cast<short4v*>(Hh + (long)wave * D + sub * 4) = hs;
        *reinterpret_cast<short4v*>(Hl + (long)wave * D + sub * 4) = ls;
    }

    float t = 0.f;
#pragma unroll
    for (int k = 0; k < 64; k++) {
        float hk;
        switch (k & 3) {
            case 0: hk = __shfl(o.x, k >> 2, 64); break;
            case 1: hk = __shfl(o.y, k >> 2, 64); break;
            case 2: hk = __shfl(o.z, k >> 2, 64); break;
            default: hk = __shfl(o.w, k >> 2, 64); break;
        }
        t += hk * S[k * 64 + lane];
    }
    short th, tl;
    bsplit(t, th, tl);
    Th[(long)wave * 64 + lane] = th;
    Tl[(long)wave * 64 + lane] = tl;
}

// ---------------- S = (Wb + Wb^T)/2 ----------------
__global__ void sym_kernel(const float* __restrict__ Wb, float* __restrict__ S) {
    int i = blockIdx.x * blockDim.x + threadIdx.x;
    if (i < 64 * 64) {
        int r = i >> 6, c = i & 63;
        S[i] = 0.5f * (Wb[r * 64 + c] + Wb[c * 64 + r]);
    }
}

// ---------------- zero the padded rows of the bf16 operands ----------------
__global__ void pad_zero(short* __restrict__ Th, short* __restrict__ Tl,
                         short* __restrict__ Hh, short* __restrict__ Hl,
                         int startRow, int padRows) {
    int i = blockIdx.x * blockDim.x + threadIdx.x;
    int tot = padRows * 64;
    if (i < tot) {
        long off = (long)startRow * 64 + i;
        Th[off] = 0; Tl[off] = 0; Hh[off] = 0; Hl[off] = 0;
    }
}

// ---------------- final: out = sigmoid(T @ H^T) via split-bf16 MFMA ----------------
// R19: 256x256 block tile (512 threads, 8 waves of 64 rows x 128 cols) -> operand
// fetch per output halves vs 128-tile (210 MB vs 409 MB). Per-accumulator MFMA
// order unchanged (ah*bh, ah*bl, al*bh) => bit-identical math. nt-store epilogue.
__global__ __launch_bounds__(512, 2) void final_mfma(
    const short* __restrict__ Th, const short* __restrict__ Tl,
    const short* __restrict__ Hh, const short* __restrict__ Hl,
    float* __restrict__ out, int n, int G, int ypx) {
    int bid = blockIdx.x;
    int xcd = bid & 7;
    int s4 = bid >> 3;
    int by = xcd * ypx + s4 % ypx;
    int bx = s4 / ypx;
    if (by >= G) return;

    int tid = threadIdx.x;
    int wave = tid >> 6, lane = tid & 63;
    int wr = wave >> 1, wc = wave & 1;      // 4x2 wave grid
    int row0 = by * 256 + wr * 64;          // wave: 64 rows
    int col0 = bx * 256 + wc * 128;         // wave: 128 cols
    int lrow = lane & 15;
    int koff = (lane >> 4) * 8;

    const short* ThB = Th + (long)(row0 + lrow) * 64 + koff;
    const short* TlB = Tl + (long)(row0 + lrow) * 64 + koff;
    const short* HhB = Hh + (long)(col0 + lrow) * 64 + koff;
    const short* HlB = Hl + (long)(col0 + lrow) * 64 + koff;

    f32x4 acc[4][8];
#pragma unroll
    for (int r = 0; r < 4; r++)
#pragma unroll
        for (int c = 0; c < 8; c++) acc[r][c] = (f32x4){0.f, 0.f, 0.f, 0.f};

#pragma unroll
    for (int ks = 0; ks < 2; ks++) {
        int kb = ks * 32;
        short8 ah[4], al[4];
#pragma unroll
        for (int r = 0; r < 4; r++) ah[r] = *reinterpret_cast<const short8*>(ThB + (long)(r * 16) * 64 + kb);
#pragma unroll
        for (int r = 0; r < 4; r++) al[r] = *reinterpret_cast<const short8*>(TlB + (long)(r * 16) * 64 + kb);

#pragma unroll
        for (int c = 0; c < 8; c++) {
            short8 bh = *reinterpret_cast<const short8*>(HhB + (long)(c * 16) * 64 + kb);
            short8 bl = *reinterpret_cast<const short8*>(HlB + (long)(c * 16) * 64 + kb);
#pragma unroll
            for (int r = 0; r < 4; r++)
                acc[r][c] = __builtin_amdgcn_mfma_f32_16x16x32_bf16(ah[r], bh, acc[r][c], 0, 0, 0);
#pragma unroll
            for (int r = 0; r < 4; r++)
                acc[r][c] = __builtin_amdgcn_mfma_f32_16x16x32_bf16(ah[r], bl, acc[r][c], 0, 0, 0);
#pragma unroll
            for (int r = 0; r < 4; r++)
                acc[r][c] = __builtin_amdgcn_mfma_f32_16x16x32_bf16(al[r], bh, acc[r][c], 0, 0, 0);
        }
    }

    // epilogue: C/D layout col = lane&15, row = (lane>>4)*4 + reg  [m89-verified]
    int orow = (lane >> 4) * 4;
    bool full = (row0 + 64 <= n) && (col0 + 128 <= n);
    if (full) {
#pragma unroll
        for (int r = 0; r < 4; r++) {
#pragma unroll
            for (int q = 0; q < 4; q++) {
                long base = (long)(row0 + r * 16 + orow + q) * n + col0 + lrow;
#pragma unroll
                for (int c = 0; c < 8; c++) {
                    float x = acc[r][c][q];
                    __builtin_nontemporal_store(__builtin_amdgcn_rcpf(1.f + __expf(-x)),
                                                out + base + c * 16);
                }
            }
        }
    } else {
#pragma unroll
        for (int r = 0; r < 4; r++) {
#pragma unroll
            for (int q = 0; q < 4; q++) {
                int i = row0 + r * 16 + orow + q;
                if (i < n) {
#pragma unroll
                    for (int c = 0; c < 8; c++) {
                        int j = col0 + c * 16 + lrow;
                        if (j < n) {
                            float x = acc[r][c][q];
                            __builtin_nontemporal_store(__builtin_amdgcn_rcpf(1.f + __expf(-x)),
                                                        out + (long)i * n + j);
                        }
                    }
                }
            }
        }
    }
}

// ---------------- launch ----------------
extern "C" void kernel_launch(void* const* d_in, const int* in_sizes, int n_in,
                              void* d_out, int out_size, void* d_ws, size_t ws_size,
                              hipStream_t stream) {
    const float* x    = (const float*)d_in[0];
    const int*   erow = (const int*)d_in[1];
    const int*   ecol = (const int*)d_in[2];
    const float* eval = (const float*)d_in[3];
    const float* W0   = (const float*)d_in[4];
    const float* W1   = (const float*)d_in[5];
    const float* W2   = (const float*)d_in[6];
    const float* Wb   = (const float*)d_in[7];
    float* out = (float*)d_out;

    int N = in_sizes[0] / 128;
    int E = in_sizes[1];
    int G = (N + 255) / 256;               // 256-tile grid
    int Npad = G * 256;

    char* w = (char*)d_ws;
    size_t off = 0;
    auto alloc = [&](size_t bytes) -> void* {
        void* p = w + off;
        off += (bytes + 255) & ~(size_t)255;
        return p;
    };
    float* bufA    = (float*)alloc((size_t)N * 128 * 4);
    float* bufB    = (float*)alloc((size_t)N * 128 * 4);
    float* S       = (float*)alloc(64 * 64 * 4);
    int*   colsort = (int*)alloc((size_t)E * 4);
    float* valsort = (float*)alloc((size_t)E * 4);
    int*   rowptr  = (int*)alloc((size_t)(N + 1) * 4);
    int*   cursor  = (int*)alloc((size_t)N * 4);
    int*   hist    = (int*)alloc((size_t)N * 4);
    int*   bsum    = (int*)alloc(64 * 4);
    short* Th      = (short*)alloc((size_t)Npad * 64 * 2);
    short* Tl      = (short*)alloc((size_t)Npad * 64 * 2);
    short* Hh      = (short*)alloc((size_t)Npad * 64 * 2);
    short* Hl      = (short*)alloc((size_t)Npad * 64 * 2);

    // CSR build (parallel scan)
    int nb = (N + 255) / 256;
    zero_i32<<<(N + 255) / 256, 256, 0, stream>>>(hist, N);
    hist_kernel<<<(E + 255) / 256, 256, 0, stream>>>(erow, hist, E);
    scan_partial<<<nb, 256, 0, stream>>>(hist, bsum, N);
    scan_bsums<<<1, 64, 0, stream>>>(bsum, nb);
    scan_final<<<nb, 256, 0, stream>>>(hist, bsum, rowptr, cursor, N);
    scatter_kernel<<<(E + 255) / 256, 256, 0, stream>>>(erow, ecol, eval, cursor, colsort, valsort, E);

    int gb8 = (N + 7) / 8;
    int spmmG = (N + 3) / 4;
    sym_kernel<<<16, 256, 0, stream>>>(Wb, S);
    // layer 1
    gemm_layer<128, 128><<<gb8, 128, 0, stream>>>(x, W0, bufB, N);
    spmm_elu_v2<128><<<spmmG, 256, 0, stream>>>(rowptr, colsort, valsort, bufB, bufA, N);
    // layer 2
    gemm_layer<128, 128><<<gb8, 128, 0, stream>>>(bufA, W1, bufB, N);
    spmm_elu_v2<128><<<spmmG, 256, 0, stream>>>(rowptr, colsort, valsort, bufB, bufA, N);
    // layer 3 (128 -> 64) + fused head
    gemm_layer<128, 64><<<gb8, 64, 0, stream>>>(bufA, W2, bufB, N);
    spmm_fused3<<<spmmG, 256, 0, stream>>>(rowptr, colsort, valsort, bufB, S, Hh, Hl, Th, Tl, N);

    int padRows = Npad - N;
    if (padRows > 0)
        pad_zero<<<(padRows * 64 + 255) / 256, 256, 0, stream>>>(Th, Tl, Hh, Hl, N, padRows);

    int ypx = (G + 7) / 8;                 // y-tiles per XCD band
    int nwg = 8 * ypx * G;                 // padded; blocks with by>=G early-exit
    final_mfma<<<nwg, 512, 0, stream>>>(Th, Tl, Hh, Hl, out, N, G, ypx);
}

// Round 19
// 309.873 us; speedup vs baseline: 1.3326x; 1.0038x over previous
//
#include <hip/hip_runtime.h>
#include <hip/hip_bf16.h>
#include <math.h>

typedef short short8 __attribute__((ext_vector_type(8)));
typedef short short4v __attribute__((ext_vector_type(4)));
typedef float f32x4 __attribute__((ext_vector_type(4)));

__device__ inline void bsplit(float x, short& h, short& l) {
    __hip_bfloat16 hb = __float2bfloat16(x);
    float hf = __bfloat162float(hb);
    __hip_bfloat16 lb = __float2bfloat16(x - hf);
    h = *reinterpret_cast<short*>(&hb);
    l = *reinterpret_cast<short*>(&lb);
}

// ---------------- CSR build ----------------

__global__ void zero_i32(int* __restrict__ p, int n) {
    int i = blockIdx.x * blockDim.x + threadIdx.x;
    if (i < n) p[i] = 0;
}

__global__ void hist_kernel(const int* __restrict__ row, int* __restrict__ hist, int E) {
    int i = blockIdx.x * blockDim.x + threadIdx.x;
    if (i < E) atomicAdd(&hist[row[i]], 1);
}

// ---- parallel scan (3 kernels, bit-identical to serial integer scan) ----
__global__ __launch_bounds__(256) void scan_partial(const int* __restrict__ hist,
                                                    int* __restrict__ bsum, int n) {
    __shared__ int ws_[4];
    int tid = threadIdx.x, lane = tid & 63, wid = tid >> 6;
    int idx = blockIdx.x * 256 + tid;
    int x = (idx < n) ? hist[idx] : 0;
#pragma unroll
    for (int m = 1; m < 64; m <<= 1) x += __shfl_xor(x, m, 64);
    if (lane == 0) ws_[wid] = x;
    __syncthreads();
    if (tid == 0) bsum[blockIdx.x] = ws_[0] + ws_[1] + ws_[2] + ws_[3];
}

// single wave scans nb (<=64) block sums in place (inclusive)
__global__ void scan_bsums(int* __restrict__ bsum, int nb) {
    int lane = threadIdx.x & 63;
    int x = (lane < nb) ? bsum[lane] : 0;
#pragma unroll
    for (int d = 1; d < 64; d <<= 1) {
        int t = __shfl_up(x, d, 64);
        if (lane >= d) x += t;
    }
    if (lane < nb) bsum[lane] = x;
}

__global__ __launch_bounds__(256) void scan_final(const int* __restrict__ hist,
                                                  const int* __restrict__ bsum,
                                                  int* __restrict__ rowptr,
                                                  int* __restrict__ cursor, int n) {
    __shared__ int wsum[4];
    int tid = threadIdx.x, lane = tid & 63, wid = tid >> 6;
    int b = blockIdx.x;
    int idx = b * 256 + tid;
    int v = (idx < n) ? hist[idx] : 0;
    int x = v;
#pragma unroll
    for (int d = 1; d < 64; d <<= 1) {
        int t = __shfl_up(x, d, 64);
        if (lane >= d) x += t;
    }
    if (lane == 63) wsum[wid] = x;
    __syncthreads();
    int add = (b > 0) ? bsum[b - 1] : 0;
    for (int w_ = 0; w_ < wid; w_++) add += wsum[w_];
    int inc = x + add;
    if (idx < n) {
        rowptr[idx + 1] = inc;
        cursor[idx] = inc - v;
    }
    if (b == 0 && tid == 0) rowptr[0] = 0;
}

__global__ void scatter_kernel(const int* __restrict__ row, const int* __restrict__ col,
                               const float* __restrict__ val, int* __restrict__ cursor,
                               int* __restrict__ colsort, float* __restrict__ valsort, int E) {
    int i = blockIdx.x * blockDim.x + threadIdx.x;
    if (i < E) {
        int r = row[i];
        int p = atomicAdd(&cursor[r], 1);
        colsort[p] = col[i];
        valsort[p] = val[i];
    }
}

// ---------------- dense layer GEMM: out[n,M] = A[n,K] @ W[K,M] ----------------
template <int K, int M>
__global__ void gemm_layer(const float* __restrict__ A, const float* __restrict__ W,
                           float* __restrict__ out, int n) {
    __shared__ float a[8 * K];
    int j = threadIdx.x;
    int row0 = blockIdx.x * 8;
    constexpr int K4 = K / 4;
    for (int idx = j; idx < 8 * K4; idx += M) {
        int r = idx / K4, k4 = idx % K4;
        float4 v = make_float4(0.f, 0.f, 0.f, 0.f);
        if (row0 + r < n) v = *reinterpret_cast<const float4*>(A + (long)(row0 + r) * K + k4 * 4);
        *reinterpret_cast<float4*>(a + r * K + k4 * 4) = v;
    }
    __syncthreads();
    float acc[8] = {0, 0, 0, 0, 0, 0, 0, 0};
#pragma unroll 8
    for (int k = 0; k < K; k++) {
        float w = W[k * M + j];
#pragma unroll
        for (int r = 0; r < 8; r++) acc[r] += a[r * K + k] * w;
    }
#pragma unroll
    for (int r = 0; r < 8; r++) {
        if (row0 + r < n) out[(long)(row0 + r) * M + j] = acc[r];
    }
}

// ---------------- SpMM v2 full-width ----------------
template <int D>
__global__ void spmm_elu_v2(const int* __restrict__ rowptr, const int* __restrict__ cols,
                            const float* __restrict__ vals, const float* __restrict__ hw,
                            float* __restrict__ out, int n) {
    constexpr int LPR = D / 4;
    constexpr int EPI = 64 / LPR;
    int wave = (blockIdx.x * blockDim.x + threadIdx.x) >> 6;
    int lane = threadIdx.x & 63;
    if (wave >= n) return;
    int sub = lane % LPR, grp = lane / LPR;
    int s = rowptr[wave], e = rowptr[wave + 1];
    float ax = 0.f, ay = 0.f, az = 0.f, aw = 0.f;
    int pe = s + grp;
    int c = 0; float v = 0.f;
    if (pe < e) { c = cols[pe]; v = vals[pe]; }
    for (int p = s; p < e; p += EPI) {
        int pn = p + EPI + grp;
        int cn = 0; float vn = 0.f;
        if (pn < e) { cn = cols[pn]; vn = vals[pn]; }
        float4 h4 = *reinterpret_cast<const float4*>(hw + (long)c * D + sub * 4);
        ax += v * h4.x; ay += v * h4.y; az += v * h4.z; aw += v * h4.w;
        c = cn; v = vn;
    }
#pragma unroll
    for (int m = LPR; m < 64; m <<= 1) {
        ax += __shfl_xor(ax, m, 64);
        ay += __shfl_xor(ay, m, 64);
        az += __shfl_xor(az, m, 64);
        aw += __shfl_xor(aw, m, 64);
    }
    if (grp == 0) {
        float4 o;
        o.x = ax > 0.f ? ax : (__expf(ax) - 1.f);
        o.y = ay > 0.f ? ay : (__expf(ay) - 1.f);
        o.z = az > 0.f ? az : (__expf(az) - 1.f);
        o.w = aw > 0.f ? aw : (__expf(aw) - 1.f);
        *reinterpret_cast<float4*>(out + (long)wave * D + sub * 4) = o;
    }
}

// ---------------- layer-3 SpMM + ELU + fused head GEMM (T = h3 @ S) ----------------
__global__ void spmm_fused3(const int* __restrict__ rowptr, const int* __restrict__ cols,
                            const float* __restrict__ vals, const float* __restrict__ hw,
                            const float* __restrict__ S,
                            short* __restrict__ Hh, short* __restrict__ Hl,
                            short* __restrict__ Th, short* __restrict__ Tl, int n) {
    constexpr int D = 64, LPR = 16, EPI = 4;
    int wave = (blockIdx.x * blockDim.x + threadIdx.x) >> 6;
    int lane = threadIdx.x & 63;
    if (wave >= n) return;
    int sub = lane % LPR, grp = lane / LPR;
    int s = rowptr[wave], e = rowptr[wave + 1];
    float ax = 0.f, ay = 0.f, az = 0.f, aw = 0.f;
    int pe = s + grp;
    int c = 0; float v = 0.f;
    if (pe < e) { c = cols[pe]; v = vals[pe]; }
    for (int p = s; p < e; p += EPI) {
        int pn = p + EPI + grp;
        int cn = 0; float vn = 0.f;
        if (pn < e) { cn = cols[pn]; vn = vals[pn]; }
        float4 h4 = *reinterpret_cast<const float4*>(hw + (long)c * D + sub * 4);
        ax += v * h4.x; ay += v * h4.y; az += v * h4.z; aw += v * h4.w;
        c = cn; v = vn;
    }
#pragma unroll
    for (int m = LPR; m < 64; m <<= 1) {
        ax += __shfl_xor(ax, m, 64);
        ay += __shfl_xor(ay, m, 64);
        az += __shfl_xor(az, m, 64);
        aw += __shfl_xor(aw, m, 64);
    }
    float4 o;
    o.x = ax > 0.f ? ax : (__expf(ax) - 1.f);
    o.y = ay > 0.f ? ay : (__expf(ay) - 1.f);
    o.z = az > 0.f ? az : (__expf(az) - 1.f);
    o.w = aw > 0.f ? aw : (__expf(aw) - 1.f);

    if (grp == 0) {
        short4v hs, ls;
        short t0, t1, t2, t3, u0, u1, u2, u3;
        bsplit(o.x, t0, u0);
        bsplit(o.y, t1, u1);
        bsplit(o.z, t2, u2);
        bsplit(o.w, t3, u3);
        hs[0] = t0; hs[1] = t1; hs[2] = t2; hs[3] = t3;
        ls[0] = u0; ls[1] = u1; ls[2] = u2; ls[3] = u3;
        *reinterpret_cast<short4v*>(Hh + (long)wave * D + sub * 4) = hs;
        *reinterpret_cast<short4v*>(Hl + (long)wave * D + sub * 4) = ls;
    }

    float t = 0.f;
#pragma unroll
    for (int k = 0; k < 64; k++) {
        float hk;
        switch (k & 3) {
            case 0: hk = __shfl(o.x, k >> 2, 64); break;
            case 1: hk = __shfl(o.y, k >> 2, 64); break;
            case 2: hk = __shfl(o.z, k >> 2, 64); break;
            default: hk = __shfl(o.w, k >> 2, 64); break;
        }
        t += hk * S[k * 64 + lane];
    }
    short th, tl;
    bsplit(t, th, tl);
    Th[(long)wave * 64 + lane] = th;
    Tl[(long)wave * 64 + lane] = tl;
}

// ---------------- S = (Wb + Wb^T)/2 ----------------
__global__ void sym_kernel(const float* __restrict__ Wb, float* __restrict__ S) {
    int i = blockIdx.x * blockDim.x + threadIdx.x;
    if (i < 64 * 64) {
        int r = i >> 6, c = i & 63;
        S[i] = 0.5f * (Wb[r * 64 + c] + Wb[c * 64 + r]);
    }
}

// ---------------- zero the padded rows of the bf16 operands ----------------
__global__ void pad_zero(short* __restrict__ Th, short* __restrict__ Tl,
                         short* __restrict__ Hh, short* __restrict__ Hl,
                         int startRow, int padRows) {
    int i = blockIdx.x * blockDim.x + threadIdx.x;
    int tot = padRows * 64;
    if (i < tot) {
        long off = (long)startRow * 64 + i;
        Th[off] = 0; Tl[off] = 0; Hh[off] = 0; Hl[off] = 0;
    }
}

// ---------------- final: out = sigmoid(T @ H^T) via split-bf16 MFMA ----------------
// R20: same 256x256 tile as R19, but __launch_bounds__(512,1): the 8 waves of
// one block still co-reside (2 waves/SIMD), VGPR budget 256 >= ~190 needed ->
// no accumulator spill (R19's (512,2) capped VGPR at 128 and spilled).
__global__ __launch_bounds__(512, 1) void final_mfma(
    const short* __restrict__ Th, const short* __restrict__ Tl,
    const short* __restrict__ Hh, const short* __restrict__ Hl,
    float* __restrict__ out, int n, int G, int ypx) {
    int bid = blockIdx.x;
    int xcd = bid & 7;
    int s4 = bid >> 3;
    int by = xcd * ypx + s4 % ypx;
    int bx = s4 / ypx;
    if (by >= G) return;

    int tid = threadIdx.x;
    int wave = tid >> 6, lane = tid & 63;
    int wr = wave >> 1, wc = wave & 1;      // 4x2 wave grid
    int row0 = by * 256 + wr * 64;          // wave: 64 rows
    int col0 = bx * 256 + wc * 128;         // wave: 128 cols
    int lrow = lane & 15;
    int koff = (lane >> 4) * 8;

    const short* ThB = Th + (long)(row0 + lrow) * 64 + koff;
    const short* TlB = Tl + (long)(row0 + lrow) * 64 + koff;
    const short* HhB = Hh + (long)(col0 + lrow) * 64 + koff;
    const short* HlB = Hl + (long)(col0 + lrow) * 64 + koff;

    f32x4 acc[4][8];
#pragma unroll
    for (int r = 0; r < 4; r++)
#pragma unroll
        for (int c = 0; c < 8; c++) acc[r][c] = (f32x4){0.f, 0.f, 0.f, 0.f};

#pragma unroll
    for (int ks = 0; ks < 2; ks++) {
        int kb = ks * 32;
        short8 ah[4], al[4];
#pragma unroll
        for (int r = 0; r < 4; r++) ah[r] = *reinterpret_cast<const short8*>(ThB + (long)(r * 16) * 64 + kb);
#pragma unroll
        for (int r = 0; r < 4; r++) al[r] = *reinterpret_cast<const short8*>(TlB + (long)(r * 16) * 64 + kb);

#pragma unroll
        for (int c = 0; c < 8; c++) {
            short8 bh = *reinterpret_cast<const short8*>(HhB + (long)(c * 16) * 64 + kb);
            short8 bl = *reinterpret_cast<const short8*>(HlB + (long)(c * 16) * 64 + kb);
#pragma unroll
            for (int r = 0; r < 4; r++)
                acc[r][c] = __builtin_amdgcn_mfma_f32_16x16x32_bf16(ah[r], bh, acc[r][c], 0, 0, 0);
#pragma unroll
            for (int r = 0; r < 4; r++)
                acc[r][c] = __builtin_amdgcn_mfma_f32_16x16x32_bf16(ah[r], bl, acc[r][c], 0, 0, 0);
#pragma unroll
            for (int r = 0; r < 4; r++)
                acc[r][c] = __builtin_amdgcn_mfma_f32_16x16x32_bf16(al[r], bh, acc[r][c], 0, 0, 0);
        }
    }

    // epilogue: C/D layout col = lane&15, row = (lane>>4)*4 + reg  [m89-verified]
    int orow = (lane >> 4) * 4;
    bool full = (row0 + 64 <= n) && (col0 + 128 <= n);
    if (full) {
#pragma unroll
        for (int r = 0; r < 4; r++) {
#pragma unroll
            for (int q = 0; q < 4; q++) {
                long base = (long)(row0 + r * 16 + orow + q) * n + col0 + lrow;
#pragma unroll
                for (int c = 0; c < 8; c++) {
                    float x = acc[r][c][q];
                    __builtin_nontemporal_store(__builtin_amdgcn_rcpf(1.f + __expf(-x)),
                                                out + base + c * 16);
                }
            }
        }
    } else {
#pragma unroll
        for (int r = 0; r < 4; r++) {
#pragma unroll
            for (int q = 0; q < 4; q++) {
                int i = row0 + r * 16 + orow + q;
                if (i < n) {
#pragma unroll
                    for (int c = 0; c < 8; c++) {
                        int j = col0 + c * 16 + lrow;
                        if (j < n) {
                            float x = acc[r][c][q];
                            __builtin_nontemporal_store(__builtin_amdgcn_rcpf(1.f + __expf(-x)),
                                                        out + (long)i * n + j);
                        }
                    }
                }
            }
        }
    }
}

// ---------------- launch ----------------
extern "C" void kernel_launch(void* const* d_in, const int* in_sizes, int n_in,
                              void* d_out, int out_size, void* d_ws, size_t ws_size,
                              hipStream_t stream) {
    const float* x    = (const float*)d_in[0];
    const int*   erow = (const int*)d_in[1];
    const int*   ecol = (const int*)d_in[2];
    const float* eval = (const float*)d_in[3];
    const float* W0   = (const float*)d_in[4];
    const float* W1   = (const float*)d_in[5];
    const float* W2   = (const float*)d_in[6];
    const float* Wb   = (const float*)d_in[7];
    float* out = (float*)d_out;

    int N = in_sizes[0] / 128;
    int E = in_sizes[1];
    int G = (N + 255) / 256;               // 256-tile grid
    int Npad = G * 256;

    char* w = (char*)d_ws;
    size_t off = 0;
    auto alloc = [&](size_t bytes) -> void* {
        void* p = w + off;
        off += (bytes + 255) & ~(size_t)255;
        return p;
    };
    float* bufA    = (float*)alloc((size_t)N * 128 * 4);
    float* bufB    = (float*)alloc((size_t)N * 128 * 4);
    float* S       = (float*)alloc(64 * 64 * 4);
    int*   colsort = (int*)alloc((size_t)E * 4);
    float* valsort = (float*)alloc((size_t)E * 4);
    int*   rowptr  = (int*)alloc((size_t)(N + 1) * 4);
    int*   cursor  = (int*)alloc((size_t)N * 4);
    int*   hist    = (int*)alloc((size_t)N * 4);
    int*   bsum    = (int*)alloc(64 * 4);
    short* Th      = (short*)alloc((size_t)Npad * 64 * 2);
    short* Tl      = (short*)alloc((size_t)Npad * 64 * 2);
    short* Hh      = (short*)alloc((size_t)Npad * 64 * 2);
    short* Hl      = (short*)alloc((size_t)Npad * 64 * 2);

    // CSR build (parallel scan)
    int nb = (N + 255) / 256;
    zero_i32<<<(N + 255) / 256, 256, 0, stream>>>(hist, N);
    hist_kernel<<<(E + 255) / 256, 256, 0, stream>>>(erow, hist, E);
    scan_partial<<<nb, 256, 0, stream>>>(hist, bsum, N);
    scan_bsums<<<1, 64, 0, stream>>>(bsum, nb);
    scan_final<<<nb, 256, 0, stream>>>(hist, bsum, rowptr, cursor, N);
    scatter_kernel<<<(E + 255) / 256, 256, 0, stream>>>(erow, ecol, eval, cursor, colsort, valsort, E);

    int gb8 = (N + 7) / 8;
    int spmmG = (N + 3) / 4;
    sym_kernel<<<16, 256, 0, stream>>>(Wb, S);
    // layer 1
    gemm_layer<128, 128><<<gb8, 128, 0, stream>>>(x, W0, bufB, N);
    spmm_elu_v2<128><<<spmmG, 256, 0, stream>>>(rowptr, colsort, valsort, bufB, bufA, N);
    // layer 2
    gemm_layer<128, 128><<<gb8, 128, 0, stream>>>(bufA, W1, bufB, N);
    spmm_elu_v2<128><<<spmmG, 256, 0, stream>>>(rowptr, colsort, valsort, bufB, bufA, N);
    // layer 3 (128 -> 64) + fused head
    gemm_layer<128, 64><<<gb8, 64, 0, stream>>>(bufA, W2, bufB, N);
    spmm_fused3<<<spmmG, 256, 0, stream>>>(rowptr, colsort, valsort, bufB, S, Hh, Hl, Th, Tl, N);

    int padRows = Npad - N;
    if (padRows > 0)
        pad_zero<<<(padRows * 64 + 255) / 256, 256, 0, stream>>>(Th, Tl, Hh, Hl, N, padRows);

    int ypx = (G + 7) / 8;                 // y-tiles per XCD band
    int nwg = 8 * ypx * G;                 // padded; blocks with by>=G early-exit
    final_mfma<<<nwg, 512, 0, stream>>>(Th, Tl, Hh, Hl, out, N, G, ypx);
}

// Round 20
// 288.342 us; speedup vs baseline: 1.4321x; 1.0747x over previous
//
#include <hip/hip_runtime.h>
#include <hip/hip_bf16.h>
#include <math.h>

typedef short short8 __attribute__((ext_vector_type(8)));
typedef short short4v __attribute__((ext_vector_type(4)));
typedef float f32x4 __attribute__((ext_vector_type(4)));

__device__ inline void bsplit(float x, short& h, short& l) {
    __hip_bfloat16 hb = __float2bfloat16(x);
    float hf = __bfloat162float(hb);
    __hip_bfloat16 lb = __float2bfloat16(x - hf);
    h = *reinterpret_cast<short*>(&hb);
    l = *reinterpret_cast<short*>(&lb);
}

// ---------------- CSR build ----------------

__global__ void zero_i32(int* __restrict__ p, int n) {
    int i = blockIdx.x * blockDim.x + threadIdx.x;
    if (i < n) p[i] = 0;
}

__global__ void hist_kernel(const int* __restrict__ row, int* __restrict__ hist, int E) {
    int i = blockIdx.x * blockDim.x + threadIdx.x;
    if (i < E) atomicAdd(&hist[row[i]], 1);
}

// ---- parallel scan (3 kernels, bit-identical to serial integer scan) ----
__global__ __launch_bounds__(256) void scan_partial(const int* __restrict__ hist,
                                                    int* __restrict__ bsum, int n) {
    __shared__ int ws_[4];
    int tid = threadIdx.x, lane = tid & 63, wid = tid >> 6;
    int idx = blockIdx.x * 256 + tid;
    int x = (idx < n) ? hist[idx] : 0;
#pragma unroll
    for (int m = 1; m < 64; m <<= 1) x += __shfl_xor(x, m, 64);
    if (lane == 0) ws_[wid] = x;
    __syncthreads();
    if (tid == 0) bsum[blockIdx.x] = ws_[0] + ws_[1] + ws_[2] + ws_[3];
}

// single wave scans nb (<=64) block sums in place (inclusive)
__global__ void scan_bsums(int* __restrict__ bsum, int nb) {
    int lane = threadIdx.x & 63;
    int x = (lane < nb) ? bsum[lane] : 0;
#pragma unroll
    for (int d = 1; d < 64; d <<= 1) {
        int t = __shfl_up(x, d, 64);
        if (lane >= d) x += t;
    }
    if (lane < nb) bsum[lane] = x;
}

__global__ __launch_bounds__(256) void scan_final(const int* __restrict__ hist,
                                                  const int* __restrict__ bsum,
                                                  int* __restrict__ rowptr,
                                                  int* __restrict__ cursor, int n) {
    __shared__ int wsum[4];
    int tid = threadIdx.x, lane = tid & 63, wid = tid >> 6;
    int b = blockIdx.x;
    int idx = b * 256 + tid;
    int v = (idx < n) ? hist[idx] : 0;
    int x = v;
#pragma unroll
    for (int d = 1; d < 64; d <<= 1) {
        int t = __shfl_up(x, d, 64);
        if (lane >= d) x += t;
    }
    if (lane == 63) wsum[wid] = x;
    __syncthreads();
    int add = (b > 0) ? bsum[b - 1] : 0;
    for (int w_ = 0; w_ < wid; w_++) add += wsum[w_];
    int inc = x + add;
    if (idx < n) {
        rowptr[idx + 1] = inc;
        cursor[idx] = inc - v;
    }
    if (b == 0 && tid == 0) rowptr[0] = 0;
}

__global__ void scatter_kernel(const int* __restrict__ row, const int* __restrict__ col,
                               const float* __restrict__ val, int* __restrict__ cursor,
                               int* __restrict__ colsort, float* __restrict__ valsort, int E) {
    int i = blockIdx.x * blockDim.x + threadIdx.x;
    if (i < E) {
        int r = row[i];
        int p = atomicAdd(&cursor[r], 1);
        colsort[p] = col[i];
        valsort[p] = val[i];
    }
}

// ---------------- dense layer GEMM: out[n,M] = A[n,K] @ W[K,M] ----------------
template <int K, int M>
__global__ void gemm_layer(const float* __restrict__ A, const float* __restrict__ W,
                           float* __restrict__ out, int n) {
    __shared__ float a[8 * K];
    int j = threadIdx.x;
    int row0 = blockIdx.x * 8;
    constexpr int K4 = K / 4;
    for (int idx = j; idx < 8 * K4; idx += M) {
        int r = idx / K4, k4 = idx % K4;
        float4 v = make_float4(0.f, 0.f, 0.f, 0.f);
        if (row0 + r < n) v = *reinterpret_cast<const float4*>(A + (long)(row0 + r) * K + k4 * 4);
        *reinterpret_cast<float4*>(a + r * K + k4 * 4) = v;
    }
    __syncthreads();
    float acc[8] = {0, 0, 0, 0, 0, 0, 0, 0};
#pragma unroll 8
    for (int k = 0; k < K; k++) {
        float w = W[k * M + j];
#pragma unroll
        for (int r = 0; r < 8; r++) acc[r] += a[r * K + k] * w;
    }
#pragma unroll
    for (int r = 0; r < 8; r++) {
        if (row0 + r < n) out[(long)(row0 + r) * M + j] = acc[r];
    }
}

// ---------------- SpMM v2 full-width ----------------
template <int D>
__global__ void spmm_elu_v2(const int* __restrict__ rowptr, const int* __restrict__ cols,
                            const float* __restrict__ vals, const float* __restrict__ hw,
                            float* __restrict__ out, int n) {
    constexpr int LPR = D / 4;
    constexpr int EPI = 64 / LPR;
    int wave = (blockIdx.x * blockDim.x + threadIdx.x) >> 6;
    int lane = threadIdx.x & 63;
    if (wave >= n) return;
    int sub = lane % LPR, grp = lane / LPR;
    int s = rowptr[wave], e = rowptr[wave + 1];
    float ax = 0.f, ay = 0.f, az = 0.f, aw = 0.f;
    int pe = s + grp;
    int c = 0; float v = 0.f;
    if (pe < e) { c = cols[pe]; v = vals[pe]; }
    for (int p = s; p < e; p += EPI) {
        int pn = p + EPI + grp;
        int cn = 0; float vn = 0.f;
        if (pn < e) { cn = cols[pn]; vn = vals[pn]; }
        float4 h4 = *reinterpret_cast<const float4*>(hw + (long)c * D + sub * 4);
        ax += v * h4.x; ay += v * h4.y; az += v * h4.z; aw += v * h4.w;
        c = cn; v = vn;
    }
#pragma unroll
    for (int m = LPR; m < 64; m <<= 1) {
        ax += __shfl_xor(ax, m, 64);
        ay += __shfl_xor(ay, m, 64);
        az += __shfl_xor(az, m, 64);
        aw += __shfl_xor(aw, m, 64);
    }
    if (grp == 0) {
        float4 o;
        o.x = ax > 0.f ? ax : (__expf(ax) - 1.f);
        o.y = ay > 0.f ? ay : (__expf(ay) - 1.f);
        o.z = az > 0.f ? az : (__expf(az) - 1.f);
        o.w = aw > 0.f ? aw : (__expf(aw) - 1.f);
        *reinterpret_cast<float4*>(out + (long)wave * D + sub * 4) = o;
    }
}

// ---------------- layer-3 SpMM + ELU + fused head GEMM (T = h3 @ S) ----------------
__global__ void spmm_fused3(const int* __restrict__ rowptr, const int* __restrict__ cols,
                            const float* __restrict__ vals, const float* __restrict__ hw,
                            const float* __restrict__ S,
                            short* __restrict__ Hh, short* __restrict__ Hl,
                            short* __restrict__ Th, short* __restrict__ Tl, int n) {
    constexpr int D = 64, LPR = 16, EPI = 4;
    int wave = (blockIdx.x * blockDim.x + threadIdx.x) >> 6;
    int lane = threadIdx.x & 63;
    if (wave >= n) return;
    int sub = lane % LPR, grp = lane / LPR;
    int s = rowptr[wave], e = rowptr[wave + 1];
    float ax = 0.f, ay = 0.f, az = 0.f, aw = 0.f;
    int pe = s + grp;
    int c = 0; float v = 0.f;
    if (pe < e) { c = cols[pe]; v = vals[pe]; }
    for (int p = s; p < e; p += EPI) {
        int pn = p + EPI + grp;
        int cn = 0; float vn = 0.f;
        if (pn < e) { cn = cols[pn]; vn = vals[pn]; }
        float4 h4 = *reinterpret_cast<const float4*>(hw + (long)c * D + sub * 4);
        ax += v * h4.x; ay += v * h4.y; az += v * h4.z; aw += v * h4.w;
        c = cn; v = vn;
    }
#pragma unroll
    for (int m = LPR; m < 64; m <<= 1) {
        ax += __shfl_xor(ax, m, 64);
        ay += __shfl_xor(ay, m, 64);
        az += __shfl_xor(az, m, 64);
        aw += __shfl_xor(aw, m, 64);
    }
    float4 o;
    o.x = ax > 0.f ? ax : (__expf(ax) - 1.f);
    o.y = ay > 0.f ? ay : (__expf(ay) - 1.f);
    o.z = az > 0.f ? az : (__expf(az) - 1.f);
    o.w = aw > 0.f ? aw : (__expf(aw) - 1.f);

    if (grp == 0) {
        short4v hs, ls;
        short t0, t1, t2, t3, u0, u1, u2, u3;
        bsplit(o.x, t0, u0);
        bsplit(o.y, t1, u1);
        bsplit(o.z, t2, u2);
        bsplit(o.w, t3, u3);
        hs[0] = t0; hs[1] = t1; hs[2] = t2; hs[3] = t3;
        ls[0] = u0; ls[1] = u1; ls[2] = u2; ls[3] = u3;
        *reinterpret_cast<short4v*>(Hh + (long)wave * D + sub * 4) = hs;
        *reinterpret_cast<short4v*>(Hl + (long)wave * D + sub * 4) = ls;
    }

    float t = 0.f;
#pragma unroll
    for (int k = 0; k < 64; k++) {
        float hk;
        switch (k & 3) {
            case 0: hk = __shfl(o.x, k >> 2, 64); break;
            case 1: hk = __shfl(o.y, k >> 2, 64); break;
            case 2: hk = __shfl(o.z, k >> 2, 64); break;
            default: hk = __shfl(o.w, k >> 2, 64); break;
        }
        t += hk * S[k * 64 + lane];
    }
    short th, tl;
    bsplit(t, th, tl);
    Th[(long)wave * 64 + lane] = th;
    Tl[(long)wave * 64 + lane] = tl;
}

// ---------------- S = (Wb + Wb^T)/2 ----------------
__global__ void sym_kernel(const float* __restrict__ Wb, float* __restrict__ S) {
    int i = blockIdx.x * blockDim.x + threadIdx.x;
    if (i < 64 * 64) {
        int r = i >> 6, c = i & 63;
        S[i] = 0.5f * (Wb[r * 64 + c] + Wb[c * 64 + r]);
    }
}

// ---------------- zero the padded rows of the bf16 operands ----------------
__global__ void pad_zero(short* __restrict__ Th, short* __restrict__ Tl,
                         short* __restrict__ Hh, short* __restrict__ Hl,
                         int startRow, int padRows) {
    int i = blockIdx.x * blockDim.x + threadIdx.x;
    int tot = padRows * 64;
    if (i < tot) {
        long off = (long)startRow * 64 + i;
        Th[off] = 0; Tl[off] = 0; Hh[off] = 0; Hl[off] = 0;
    }
}

// ---------------- final: out = sigmoid(T @ H^T) via split-bf16 MFMA ----------------
// Best-measured config (R12/R15): 128x128 tile, (256,2), direct nt-stores.
__global__ __launch_bounds__(256, 2) void final_mfma(
    const short* __restrict__ Th, const short* __restrict__ Tl,
    const short* __restrict__ Hh, const short* __restrict__ Hl,
    float* __restrict__ out, int n, int G, int ypx) {
    int bid = blockIdx.x;
    int xcd = bid & 7;
    int s4 = bid >> 3;
    int by = xcd * ypx + s4 % ypx;
    int bx = s4 / ypx;
    if (by >= G) return;

    int tid = threadIdx.x;
    int wave = tid >> 6, lane = tid & 63;
    int row0 = by * 128 + (wave >> 1) * 64;
    int col0 = bx * 128 + (wave & 1) * 64;
    int lrow = lane & 15;
    int koff = (lane >> 4) * 8;

    const short* ThB = Th + (long)(row0 + lrow) * 64 + koff;
    const short* TlB = Tl + (long)(row0 + lrow) * 64 + koff;
    const short* HhB = Hh + (long)(col0 + lrow) * 64 + koff;
    const short* HlB = Hl + (long)(col0 + lrow) * 64 + koff;

    f32x4 acc[4][4];
#pragma unroll
    for (int r = 0; r < 4; r++)
#pragma unroll
        for (int c = 0; c < 4; c++) acc[r][c] = (f32x4){0.f, 0.f, 0.f, 0.f};

#pragma unroll
    for (int ks = 0; ks < 2; ks++) {
        int kb = ks * 32;
        short8 ah[4], al[4];
#pragma unroll
        for (int r = 0; r < 4; r++) ah[r] = *reinterpret_cast<const short8*>(ThB + (long)(r * 16) * 64 + kb);
#pragma unroll
        for (int r = 0; r < 4; r++) al[r] = *reinterpret_cast<const short8*>(TlB + (long)(r * 16) * 64 + kb);

#pragma unroll
        for (int c = 0; c < 4; c++) {
            short8 bh = *reinterpret_cast<const short8*>(HhB + (long)(c * 16) * 64 + kb);
            short8 bl = *reinterpret_cast<const short8*>(HlB + (long)(c * 16) * 64 + kb);
#pragma unroll
            for (int r = 0; r < 4; r++)
                acc[r][c] = __builtin_amdgcn_mfma_f32_16x16x32_bf16(ah[r], bh, acc[r][c], 0, 0, 0);
#pragma unroll
            for (int r = 0; r < 4; r++)
                acc[r][c] = __builtin_amdgcn_mfma_f32_16x16x32_bf16(ah[r], bl, acc[r][c], 0, 0, 0);
#pragma unroll
            for (int r = 0; r < 4; r++)
                acc[r][c] = __builtin_amdgcn_mfma_f32_16x16x32_bf16(al[r], bh, acc[r][c], 0, 0, 0);
        }
    }

    // epilogue: C/D layout col = lane&15, row = (lane>>4)*4 + reg  [m89-verified]
    int orow = (lane >> 4) * 4;
    bool full = (row0 + 64 <= n) && (col0 + 64 <= n);
    if (full) {
#pragma unroll
        for (int r = 0; r < 4; r++) {
#pragma unroll
            for (int q = 0; q < 4; q++) {
                long base = (long)(row0 + r * 16 + orow + q) * n + col0 + lrow;
#pragma unroll
                for (int c = 0; c < 4; c++) {
                    float x = acc[r][c][q];
                    __builtin_nontemporal_store(__builtin_amdgcn_rcpf(1.f + __expf(-x)),
                                                out + base + c * 16);
                }
            }
        }
    } else {
#pragma unroll
        for (int r = 0; r < 4; r++) {
#pragma unroll
            for (int q = 0; q < 4; q++) {
                int i = row0 + r * 16 + orow + q;
                if (i < n) {
#pragma unroll
                    for (int c = 0; c < 4; c++) {
                        int j = col0 + c * 16 + lrow;
                        if (j < n) {
                            float x = acc[r][c][q];
                            __builtin_nontemporal_store(__builtin_amdgcn_rcpf(1.f + __expf(-x)),
                                                        out + (long)i * n + j);
                        }
                    }
                }
            }
        }
    }
}

// ---------------- launch ----------------
extern "C" void kernel_launch(void* const* d_in, const int* in_sizes, int n_in,
                              void* d_out, int out_size, void* d_ws, size_t ws_size,
                              hipStream_t stream) {
    const float* x    = (const float*)d_in[0];
    const int*   erow = (const int*)d_in[1];
    const int*   ecol = (const int*)d_in[2];
    const float* eval = (const float*)d_in[3];
    const float* W0   = (const float*)d_in[4];
    const float* W1   = (const float*)d_in[5];
    const float* W2   = (const float*)d_in[6];
    const float* Wb   = (const float*)d_in[7];
    float* out = (float*)d_out;

    int N = in_sizes[0] / 128;
    int E = in_sizes[1];
    int G = (N + 127) / 128;
    int Npad = G * 128;

    char* w = (char*)d_ws;
    size_t off = 0;
    auto alloc = [&](size_t bytes) -> void* {
        void* p = w + off;
        off += (bytes + 255) & ~(size_t)255;
        return p;
    };
    float* bufA    = (float*)alloc((size_t)N * 128 * 4);
    float* bufB    = (float*)alloc((size_t)N * 128 * 4);
    float* S       = (float*)alloc(64 * 64 * 4);
    int*   colsort = (int*)alloc((size_t)E * 4);
    float* valsort = (float*)alloc((size_t)E * 4);
    int*   rowptr  = (int*)alloc((size_t)(N + 1) * 4);
    int*   cursor  = (int*)alloc((size_t)N * 4);
    int*   hist    = (int*)alloc((size_t)N * 4);
    int*   bsum    = (int*)alloc(64 * 4);
    short* Th      = (short*)alloc((size_t)Npad * 64 * 2);
    short* Tl      = (short*)alloc((size_t)Npad * 64 * 2);
    short* Hh      = (short*)alloc((size_t)Npad * 64 * 2);
    short* Hl      = (short*)alloc((size_t)Npad * 64 * 2);

    // CSR build (parallel scan)
    int nb = (N + 255) / 256;
    zero_i32<<<(N + 255) / 256, 256, 0, stream>>>(hist, N);
    hist_kernel<<<(E + 255) / 256, 256, 0, stream>>>(erow, hist, E);
    scan_partial<<<nb, 256, 0, stream>>>(hist, bsum, N);
    scan_bsums<<<1, 64, 0, stream>>>(bsum, nb);
    scan_final<<<nb, 256, 0, stream>>>(hist, bsum, rowptr, cursor, N);
    scatter_kernel<<<(E + 255) / 256, 256, 0, stream>>>(erow, ecol, eval, cursor, colsort, valsort, E);

    int gb8 = (N + 7) / 8;
    int spmmG = (N + 3) / 4;
    sym_kernel<<<16, 256, 0, stream>>>(Wb, S);
    // layer 1
    gemm_layer<128, 128><<<gb8, 128, 0, stream>>>(x, W0, bufB, N);
    spmm_elu_v2<128><<<spmmG, 256, 0, stream>>>(rowptr, colsort, valsort, bufB, bufA, N);
    // layer 2
    gemm_layer<128, 128><<<gb8, 128, 0, stream>>>(bufA, W1, bufB, N);
    spmm_elu_v2<128><<<spmmG, 256, 0, stream>>>(rowptr, colsort, valsort, bufB, bufA, N);
    // layer 3 (128 -> 64) + fused head
    gemm_layer<128, 64><<<gb8, 64, 0, stream>>>(bufA, W2, bufB, N);
    spmm_fused3<<<spmmG, 256, 0, stream>>>(rowptr, colsort, valsort, bufB, S, Hh, Hl, Th, Tl, N);

    int padRows = Npad - N;
    if (padRows > 0)
        pad_zero<<<(padRows * 64 + 255) / 256, 256, 0, stream>>>(Th, Tl, Hh, Hl, N, padRows);

    int ypx = (G + 7) / 8;                 // y-tiles per XCD band
    int nwg = 8 * ypx * G;                 // padded; blocks with by>=G early-exit
    final_mfma<<<nwg, 256, 0, stream>>>(Th, Tl, Hh, Hl, out, N, G, ypx);
}

// Round 21
// 279.516 us; speedup vs baseline: 1.4773x; 1.0316x over previous
//
#include <hip/hip_runtime.h>
#include <hip/hip_bf16.h>
#include <math.h>

typedef short short8 __attribute__((ext_vector_type(8)));
typedef short short4v __attribute__((ext_vector_type(4)));
typedef float f32x4 __attribute__((ext_vector_type(4)));

__device__ inline void bsplit(float x, short& h, short& l) {
    __hip_bfloat16 hb = __float2bfloat16(x);
    float hf = __bfloat162float(hb);
    __hip_bfloat16 lb = __float2bfloat16(x - hf);
    h = *reinterpret_cast<short*>(&hb);
    l = *reinterpret_cast<short*>(&lb);
}

// ---------------- CSR build ----------------

__global__ void zero_i32(int* __restrict__ p, int n) {
    int i = blockIdx.x * blockDim.x + threadIdx.x;
    if (i < n) p[i] = 0;
}

__global__ void hist_kernel(const int* __restrict__ row, int* __restrict__ hist, int E) {
    int i = blockIdx.x * blockDim.x + threadIdx.x;
    if (i < E) atomicAdd(&hist[row[i]], 1);
}

// ---- parallel scan (3 kernels, bit-identical to serial integer scan) ----
__global__ __launch_bounds__(256) void scan_partial(const int* __restrict__ hist,
                                                    int* __restrict__ bsum, int n) {
    __shared__ int ws_[4];
    int tid = threadIdx.x, lane = tid & 63, wid = tid >> 6;
    int idx = blockIdx.x * 256 + tid;
    int x = (idx < n) ? hist[idx] : 0;
#pragma unroll
    for (int m = 1; m < 64; m <<= 1) x += __shfl_xor(x, m, 64);
    if (lane == 0) ws_[wid] = x;
    __syncthreads();
    if (tid == 0) bsum[blockIdx.x] = ws_[0] + ws_[1] + ws_[2] + ws_[3];
}

// single wave scans nb (<=64) block sums in place (inclusive)
__global__ void scan_bsums(int* __restrict__ bsum, int nb) {
    int lane = threadIdx.x & 63;
    int x = (lane < nb) ? bsum[lane] : 0;
#pragma unroll
    for (int d = 1; d < 64; d <<= 1) {
        int t = __shfl_up(x, d, 64);
        if (lane >= d) x += t;
    }
    if (lane < nb) bsum[lane] = x;
}

__global__ __launch_bounds__(256) void scan_final(const int* __restrict__ hist,
                                                  const int* __restrict__ bsum,
                                                  int* __restrict__ rowptr,
                                                  int* __restrict__ cursor, int n) {
    __shared__ int wsum[4];
    int tid = threadIdx.x, lane = tid & 63, wid = tid >> 6;
    int b = blockIdx.x;
    int idx = b * 256 + tid;
    int v = (idx < n) ? hist[idx] : 0;
    int x = v;
#pragma unroll
    for (int d = 1; d < 64; d <<= 1) {
        int t = __shfl_up(x, d, 64);
        if (lane >= d) x += t;
    }
    if (lane == 63) wsum[wid] = x;
    __syncthreads();
    int add = (b > 0) ? bsum[b - 1] : 0;
    for (int w_ = 0; w_ < wid; w_++) add += wsum[w_];
    int inc = x + add;
    if (idx < n) {
        rowptr[idx + 1] = inc;
        cursor[idx] = inc - v;
    }
    if (b == 0 && tid == 0) rowptr[0] = 0;
}

__global__ void scatter_kernel(const int* __restrict__ row, const int* __restrict__ col,
                               const float* __restrict__ val, int* __restrict__ cursor,
                               int* __restrict__ colsort, float* __restrict__ valsort, int E) {
    int i = blockIdx.x * blockDim.x + threadIdx.x;
    if (i < E) {
        int r = row[i];
        int p = atomicAdd(&cursor[r], 1);
        colsort[p] = col[i];
        valsort[p] = val[i];
    }
}

// ---------------- dense layer GEMM: out[n,M] = A[n,K] @ W[K,M] ----------------
template <int K, int M>
__global__ void gemm_layer(const float* __restrict__ A, const float* __restrict__ W,
                           float* __restrict__ out, int n) {
    __shared__ float a[8 * K];
    int j = threadIdx.x;
    int row0 = blockIdx.x * 8;
    constexpr int K4 = K / 4;
    for (int idx = j; idx < 8 * K4; idx += M) {
        int r = idx / K4, k4 = idx % K4;
        float4 v = make_float4(0.f, 0.f, 0.f, 0.f);
        if (row0 + r < n) v = *reinterpret_cast<const float4*>(A + (long)(row0 + r) * K + k4 * 4);
        *reinterpret_cast<float4*>(a + r * K + k4 * 4) = v;
    }
    __syncthreads();
    float acc[8] = {0, 0, 0, 0, 0, 0, 0, 0};
#pragma unroll 8
    for (int k = 0; k < K; k++) {
        float w = W[k * M + j];
#pragma unroll
        for (int r = 0; r < 8; r++) acc[r] += a[r * K + k] * w;
    }
#pragma unroll
    for (int r = 0; r < 8; r++) {
        if (row0 + r < n) out[(long)(row0 + r) * M + j] = acc[r];
    }
}

// ---------------- SpMM v2 full-width ----------------
template <int D>
__global__ void spmm_elu_v2(const int* __restrict__ rowptr, const int* __restrict__ cols,
                            const float* __restrict__ vals, const float* __restrict__ hw,
                            float* __restrict__ out, int n) {
    constexpr int LPR = D / 4;
    constexpr int EPI = 64 / LPR;
    int wave = (blockIdx.x * blockDim.x + threadIdx.x) >> 6;
    int lane = threadIdx.x & 63;
    if (wave >= n) return;
    int sub = lane % LPR, grp = lane / LPR;
    int s = rowptr[wave], e = rowptr[wave + 1];
    float ax = 0.f, ay = 0.f, az = 0.f, aw = 0.f;
    int pe = s + grp;
    int c = 0; float v = 0.f;
    if (pe < e) { c = cols[pe]; v = vals[pe]; }
    for (int p = s; p < e; p += EPI) {
        int pn = p + EPI + grp;
        int cn = 0; float vn = 0.f;
        if (pn < e) { cn = cols[pn]; vn = vals[pn]; }
        float4 h4 = *reinterpret_cast<const float4*>(hw + (long)c * D + sub * 4);
        ax += v * h4.x; ay += v * h4.y; az += v * h4.z; aw += v * h4.w;
        c = cn; v = vn;
    }
#pragma unroll
    for (int m = LPR; m < 64; m <<= 1) {
        ax += __shfl_xor(ax, m, 64);
        ay += __shfl_xor(ay, m, 64);
        az += __shfl_xor(az, m, 64);
        aw += __shfl_xor(aw, m, 64);
    }
    if (grp == 0) {
        float4 o;
        o.x = ax > 0.f ? ax : (__expf(ax) - 1.f);
        o.y = ay > 0.f ? ay : (__expf(ay) - 1.f);
        o.z = az > 0.f ? az : (__expf(az) - 1.f);
        o.w = aw > 0.f ? aw : (__expf(aw) - 1.f);
        *reinterpret_cast<float4*>(out + (long)wave * D + sub * 4) = o;
    }
}

// ---------------- layer-3 SpMM + ELU + fused head GEMM (T = h3 @ S) ----------------
__global__ void spmm_fused3(const int* __restrict__ rowptr, const int* __restrict__ cols,
                            const float* __restrict__ vals, const float* __restrict__ hw,
                            const float* __restrict__ S,
                            short* __restrict__ Hh, short* __restrict__ Hl,
                            short* __restrict__ Th, short* __restrict__ Tl, int n) {
    constexpr int D = 64, LPR = 16, EPI = 4;
    int wave = (blockIdx.x * blockDim.x + threadIdx.x) >> 6;
    int lane = threadIdx.x & 63;
    if (wave >= n) return;
    int sub = lane % LPR, grp = lane / LPR;
    int s = rowptr[wave], e = rowptr[wave + 1];
    float ax = 0.f, ay = 0.f, az = 0.f, aw = 0.f;
    int pe = s + grp;
    int c = 0; float v = 0.f;
    if (pe < e) { c = cols[pe]; v = vals[pe]; }
    for (int p = s; p < e; p += EPI) {
        int pn = p + EPI + grp;
        int cn = 0; float vn = 0.f;
        if (pn < e) { cn = cols[pn]; vn = vals[pn]; }
        float4 h4 = *reinterpret_cast<const float4*>(hw + (long)c * D + sub * 4);
        ax += v * h4.x; ay += v * h4.y; az += v * h4.z; aw += v * h4.w;
        c = cn; v = vn;
    }
#pragma unroll
    for (int m = LPR; m < 64; m <<= 1) {
        ax += __shfl_xor(ax, m, 64);
        ay += __shfl_xor(ay, m, 64);
        az += __shfl_xor(az, m, 64);
        aw += __shfl_xor(aw, m, 64);
    }
    float4 o;
    o.x = ax > 0.f ? ax : (__expf(ax) - 1.f);
    o.y = ay > 0.f ? ay : (__expf(ay) - 1.f);
    o.z = az > 0.f ? az : (__expf(az) - 1.f);
    o.w = aw > 0.f ? aw : (__expf(aw) - 1.f);

    if (grp == 0) {
        short4v hs, ls;
        short t0, t1, t2, t3, u0, u1, u2, u3;
        bsplit(o.x, t0, u0);
        bsplit(o.y, t1, u1);
        bsplit(o.z, t2, u2);
        bsplit(o.w, t3, u3);
        hs[0] = t0; hs[1] = t1; hs[2] = t2; hs[3] = t3;
        ls[0] = u0; ls[1] = u1; ls[2] = u2; ls[3] = u3;
        *reinterpret_cast<short4v*>(Hh + (long)wave * D + sub * 4) = hs;
        *reinterpret_cast<short4v*>(Hl + (long)wave * D + sub * 4) = ls;
    }

    float t = 0.f;
#pragma unroll
    for (int k = 0; k < 64; k++) {
        float hk;
        switch (k & 3) {
            case 0: hk = __shfl(o.x, k >> 2, 64); break;
            case 1: hk = __shfl(o.y, k >> 2, 64); break;
            case 2: hk = __shfl(o.z, k >> 2, 64); break;
            default: hk = __shfl(o.w, k >> 2, 64); break;
        }
        t += hk * S[k * 64 + lane];
    }
    short th, tl;
    bsplit(t, th, tl);
    Th[(long)wave * 64 + lane] = th;
    Tl[(long)wave * 64 + lane] = tl;
}

// ---------------- S = (Wb + Wb^T)/2 ----------------
__global__ void sym_kernel(const float* __restrict__ Wb, float* __restrict__ S) {
    int i = blockIdx.x * blockDim.x + threadIdx.x;
    if (i < 64 * 64) {
        int r = i >> 6, c = i & 63;
        S[i] = 0.5f * (Wb[r * 64 + c] + Wb[c * 64 + r]);
    }
}

// ---------------- zero the padded rows of the bf16 operands ----------------
__global__ void pad_zero(short* __restrict__ Th, short* __restrict__ Tl,
                         short* __restrict__ Hh, short* __restrict__ Hl,
                         int startRow, int padRows) {
    int i = blockIdx.x * blockDim.x + threadIdx.x;
    int tot = padRows * 64;
    if (i < tot) {
        long off = (long)startRow * 64 + i;
        Th[off] = 0; Tl[off] = 0; Hh[off] = 0; Hl[off] = 0;
    }
}

// ---------------- final: out = sigmoid(T @ H^T) via split-bf16 MFMA ----------------
// R22: fragment-column interleave. Fragment c covers output cols {col0+4m+c}
// (B loads H row col0+lrow*4+c), so one lane's acc[r][0..3][q] are 4 CONSECUTIVE
// output floats -> f32x4 nt-store (16B/lane, 1KB/wave-instruction) instead of
// scattered 4B stores in 64B granules. Bit-identical math (pure permutation of
// fragment<->column assignment; per-element k-order unchanged).
__global__ __launch_bounds__(256, 2) void final_mfma(
    const short* __restrict__ Th, const short* __restrict__ Tl,
    const short* __restrict__ Hh, const short* __restrict__ Hl,
    float* __restrict__ out, int n, int G, int ypx) {
    int bid = blockIdx.x;
    int xcd = bid & 7;
    int s4 = bid >> 3;
    int by = xcd * ypx + s4 % ypx;
    int bx = s4 / ypx;
    if (by >= G) return;

    int tid = threadIdx.x;
    int wave = tid >> 6, lane = tid & 63;
    int row0 = by * 128 + (wave >> 1) * 64;
    int col0 = bx * 128 + (wave & 1) * 64;
    int lrow = lane & 15;
    int koff = (lane >> 4) * 8;

    const short* ThB = Th + (long)(row0 + lrow) * 64 + koff;
    const short* TlB = Tl + (long)(row0 + lrow) * 64 + koff;
    // interleaved B: fragment c loads H row col0 + lrow*4 + c
    const short* HhB = Hh + (long)(col0 + lrow * 4) * 64 + koff;
    const short* HlB = Hl + (long)(col0 + lrow * 4) * 64 + koff;

    f32x4 acc[4][4];
#pragma unroll
    for (int r = 0; r < 4; r++)
#pragma unroll
        for (int c = 0; c < 4; c++) acc[r][c] = (f32x4){0.f, 0.f, 0.f, 0.f};

#pragma unroll
    for (int ks = 0; ks < 2; ks++) {
        int kb = ks * 32;
        short8 ah[4], al[4];
#pragma unroll
        for (int r = 0; r < 4; r++) ah[r] = *reinterpret_cast<const short8*>(ThB + (long)(r * 16) * 64 + kb);
#pragma unroll
        for (int r = 0; r < 4; r++) al[r] = *reinterpret_cast<const short8*>(TlB + (long)(r * 16) * 64 + kb);

#pragma unroll
        for (int c = 0; c < 4; c++) {
            short8 bh = *reinterpret_cast<const short8*>(HhB + (long)c * 64 + kb);
            short8 bl = *reinterpret_cast<const short8*>(HlB + (long)c * 64 + kb);
#pragma unroll
            for (int r = 0; r < 4; r++)
                acc[r][c] = __builtin_amdgcn_mfma_f32_16x16x32_bf16(ah[r], bh, acc[r][c], 0, 0, 0);
#pragma unroll
            for (int r = 0; r < 4; r++)
                acc[r][c] = __builtin_amdgcn_mfma_f32_16x16x32_bf16(ah[r], bl, acc[r][c], 0, 0, 0);
#pragma unroll
            for (int r = 0; r < 4; r++)
                acc[r][c] = __builtin_amdgcn_mfma_f32_16x16x32_bf16(al[r], bh, acc[r][c], 0, 0, 0);
        }
    }

    // epilogue: C/D layout col(fragment) = lane&15, row = (lane>>4)*4 + reg;
    // with interleave, lane's fragment-col m=lrow maps to output cols col0+4*lrow+c.
    int orow = (lane >> 4) * 4;
    bool full = (row0 + 64 <= n) && (col0 + 64 <= n);
    if (full) {
#pragma unroll
        for (int r = 0; r < 4; r++) {
#pragma unroll
            for (int q = 0; q < 4; q++) {
                long base = (long)(row0 + r * 16 + orow + q) * n + col0 + lrow * 4;
                f32x4 v;
                v[0] = __builtin_amdgcn_rcpf(1.f + __expf(-acc[r][0][q]));
                v[1] = __builtin_amdgcn_rcpf(1.f + __expf(-acc[r][1][q]));
                v[2] = __builtin_amdgcn_rcpf(1.f + __expf(-acc[r][2][q]));
                v[3] = __builtin_amdgcn_rcpf(1.f + __expf(-acc[r][3][q]));
                __builtin_nontemporal_store(v, reinterpret_cast<f32x4*>(out + base));
            }
        }
    } else {
#pragma unroll
        for (int r = 0; r < 4; r++) {
#pragma unroll
            for (int q = 0; q < 4; q++) {
                int i = row0 + r * 16 + orow + q;
                if (i < n) {
#pragma unroll
                    for (int c = 0; c < 4; c++) {
                        int j = col0 + lrow * 4 + c;
                        if (j < n) {
                            float x = acc[r][c][q];
                            __builtin_nontemporal_store(__builtin_amdgcn_rcpf(1.f + __expf(-x)),
                                                        out + (long)i * n + j);
                        }
                    }
                }
            }
        }
    }
}

// ---------------- launch ----------------
extern "C" void kernel_launch(void* const* d_in, const int* in_sizes, int n_in,
                              void* d_out, int out_size, void* d_ws, size_t ws_size,
                              hipStream_t stream) {
    const float* x    = (const float*)d_in[0];
    const int*   erow = (const int*)d_in[1];
    const int*   ecol = (const int*)d_in[2];
    const float* eval = (const float*)d_in[3];
    const float* W0   = (const float*)d_in[4];
    const float* W1   = (const float*)d_in[5];
    const float* W2   = (const float*)d_in[6];
    const float* Wb   = (const float*)d_in[7];
    float* out = (float*)d_out;

    int N = in_sizes[0] / 128;
    int E = in_sizes[1];
    int G = (N + 127) / 128;
    int Npad = G * 128;

    char* w = (char*)d_ws;
    size_t off = 0;
    auto alloc = [&](size_t bytes) -> void* {
        void* p = w + off;
        off += (bytes + 255) & ~(size_t)255;
        return p;
    };
    float* bufA    = (float*)alloc((size_t)N * 128 * 4);
    float* bufB    = (float*)alloc((size_t)N * 128 * 4);
    float* S       = (float*)alloc(64 * 64 * 4);
    int*   colsort = (int*)alloc((size_t)E * 4);
    float* valsort = (float*)alloc((size_t)E * 4);
    int*   rowptr  = (int*)alloc((size_t)(N + 1) * 4);
    int*   cursor  = (int*)alloc((size_t)N * 4);
    int*   hist    = (int*)alloc((size_t)N * 4);
    int*   bsum    = (int*)alloc(64 * 4);
    short* Th      = (short*)alloc((size_t)Npad * 64 * 2);
    short* Tl      = (short*)alloc((size_t)Npad * 64 * 2);
    short* Hh      = (short*)alloc((size_t)Npad * 64 * 2);
    short* Hl      = (short*)alloc((size_t)Npad * 64 * 2);

    // CSR build (parallel scan)
    int nb = (N + 255) / 256;
    zero_i32<<<(N + 255) / 256, 256, 0, stream>>>(hist, N);
    hist_kernel<<<(E + 255) / 256, 256, 0, stream>>>(erow, hist, E);
    scan_partial<<<nb, 256, 0, stream>>>(hist, bsum, N);
    scan_bsums<<<1, 64, 0, stream>>>(bsum, nb);
    scan_final<<<nb, 256, 0, stream>>>(hist, bsum, rowptr, cursor, N);
    scatter_kernel<<<(E + 255) / 256, 256, 0, stream>>>(erow, ecol, eval, cursor, colsort, valsort, E);

    int gb8 = (N + 7) / 8;
    int spmmG = (N + 3) / 4;
    sym_kernel<<<16, 256, 0, stream>>>(Wb, S);
    // layer 1
    gemm_layer<128, 128><<<gb8, 128, 0, stream>>>(x, W0, bufB, N);
    spmm_elu_v2<128><<<spmmG, 256, 0, stream>>>(rowptr, colsort, valsort, bufB, bufA, N);
    // layer 2
    gemm_layer<128, 128><<<gb8, 128, 0, stream>>>(bufA, W1, bufB, N);
    spmm_elu_v2<128><<<spmmG, 256, 0, stream>>>(rowptr, colsort, valsort, bufB, bufA, N);
    // layer 3 (128 -> 64) + fused head
    gemm_layer<128, 64><<<gb8, 64, 0, stream>>>(bufA, W2, bufB, N);
    spmm_fused3<<<spmmG, 256, 0, stream>>>(rowptr, colsort, valsort, bufB, S, Hh, Hl, Th, Tl, N);

    int padRows = Npad - N;
    if (padRows > 0)
        pad_zero<<<(padRows * 64 + 255) / 256, 256, 0, stream>>>(Th, Tl, Hh, Hl, N, padRows);

    int ypx = (G + 7) / 8;                 // y-tiles per XCD band
    int nwg = 8 * ypx * G;                 // padded; blocks with by>=G early-exit
    final_mfma<<<nwg, 256, 0, stream>>>(Th, Tl, Hh, Hl, out, N, G, ypx);
}

// Round 22
// 269.328 us; speedup vs baseline: 1.5332x; 1.0378x over previous
//
#include <hip/hip_runtime.h>
#include <hip/hip_bf16.h>
#include <hip/hip_fp16.h>
#include <math.h>

typedef short short8 __attribute__((ext_vector_type(8)));
typedef short short4v __attribute__((ext_vector_type(4)));
typedef float f32x4 __attribute__((ext_vector_type(4)));

__device__ inline short f2h(float x) {
    __half h = __float2half(x);
    return *reinterpret_cast<short*>(&h);
}

// ---------------- CSR build ----------------

__global__ void zero_i32(int* __restrict__ p, int n) {
    int i = blockIdx.x * blockDim.x + threadIdx.x;
    if (i < n) p[i] = 0;
}

__global__ void hist_kernel(const int* __restrict__ row, int* __restrict__ hist, int E) {
    int i = blockIdx.x * blockDim.x + threadIdx.x;
    if (i < E) atomicAdd(&hist[row[i]], 1);
}

// ---- parallel scan (3 kernels, bit-identical to serial integer scan) ----
__global__ __launch_bounds__(256) void scan_partial(const int* __restrict__ hist,
                                                    int* __restrict__ bsum, int n) {
    __shared__ int ws_[4];
    int tid = threadIdx.x, lane = tid & 63, wid = tid >> 6;
    int idx = blockIdx.x * 256 + tid;
    int x = (idx < n) ? hist[idx] : 0;
#pragma unroll
    for (int m = 1; m < 64; m <<= 1) x += __shfl_xor(x, m, 64);
    if (lane == 0) ws_[wid] = x;
    __syncthreads();
    if (tid == 0) bsum[blockIdx.x] = ws_[0] + ws_[1] + ws_[2] + ws_[3];
}

__global__ void scan_bsums(int* __restrict__ bsum, int nb) {
    int lane = threadIdx.x & 63;
    int x = (lane < nb) ? bsum[lane] : 0;
#pragma unroll
    for (int d = 1; d < 64; d <<= 1) {
        int t = __shfl_up(x, d, 64);
        if (lane >= d) x += t;
    }
    if (lane < nb) bsum[lane] = x;
}

__global__ __launch_bounds__(256) void scan_final(const int* __restrict__ hist,
                                                  const int* __restrict__ bsum,
                                                  int* __restrict__ rowptr,
                                                  int* __restrict__ cursor, int n) {
    __shared__ int wsum[4];
    int tid = threadIdx.x, lane = tid & 63, wid = tid >> 6;
    int b = blockIdx.x;
    int idx = b * 256 + tid;
    int v = (idx < n) ? hist[idx] : 0;
    int x = v;
#pragma unroll
    for (int d = 1; d < 64; d <<= 1) {
        int t = __shfl_up(x, d, 64);
        if (lane >= d) x += t;
    }
    if (lane == 63) wsum[wid] = x;
    __syncthreads();
    int add = (b > 0) ? bsum[b - 1] : 0;
    for (int w_ = 0; w_ < wid; w_++) add += wsum[w_];
    int inc = x + add;
    if (idx < n) {
        rowptr[idx + 1] = inc;
        cursor[idx] = inc - v;
    }
    if (b == 0 && tid == 0) rowptr[0] = 0;
}

__global__ void scatter_kernel(const int* __restrict__ row, const int* __restrict__ col,
                               const float* __restrict__ val, int* __restrict__ cursor,
                               int* __restrict__ colsort, float* __restrict__ valsort, int E) {
    int i = blockIdx.x * blockDim.x + threadIdx.x;
    if (i < E) {
        int r = row[i];
        int p = atomicAdd(&cursor[r], 1);
        colsort[p] = col[i];
        valsort[p] = val[i];
    }
}

// ---------------- dense layer GEMM: out[n,M] = A[n,K] @ W[K,M] ----------------
template <int K, int M>
__global__ void gemm_layer(const float* __restrict__ A, const float* __restrict__ W,
                           float* __restrict__ out, int n) {
    __shared__ float a[8 * K];
    int j = threadIdx.x;
    int row0 = blockIdx.x * 8;
    constexpr int K4 = K / 4;
    for (int idx = j; idx < 8 * K4; idx += M) {
        int r = idx / K4, k4 = idx % K4;
        float4 v = make_float4(0.f, 0.f, 0.f, 0.f);
        if (row0 + r < n) v = *reinterpret_cast<const float4*>(A + (long)(row0 + r) * K + k4 * 4);
        *reinterpret_cast<float4*>(a + r * K + k4 * 4) = v;
    }
    __syncthreads();
    float acc[8] = {0, 0, 0, 0, 0, 0, 0, 0};
#pragma unroll 8
    for (int k = 0; k < K; k++) {
        float w = W[k * M + j];
#pragma unroll
        for (int r = 0; r < 8; r++) acc[r] += a[r * K + k] * w;
    }
#pragma unroll
    for (int r = 0; r < 8; r++) {
        if (row0 + r < n) out[(long)(row0 + r) * M + j] = acc[r];
    }
}

// ---------------- SpMM v2 full-width ----------------
template <int D>
__global__ void spmm_elu_v2(const int* __restrict__ rowptr, const int* __restrict__ cols,
                            const float* __restrict__ vals, const float* __restrict__ hw,
                            float* __restrict__ out, int n) {
    constexpr int LPR = D / 4;
    constexpr int EPI = 64 / LPR;
    int wave = (blockIdx.x * blockDim.x + threadIdx.x) >> 6;
    int lane = threadIdx.x & 63;
    if (wave >= n) return;
    int sub = lane % LPR, grp = lane / LPR;
    int s = rowptr[wave], e = rowptr[wave + 1];
    float ax = 0.f, ay = 0.f, az = 0.f, aw = 0.f;
    int pe = s + grp;
    int c = 0; float v = 0.f;
    if (pe < e) { c = cols[pe]; v = vals[pe]; }
    for (int p = s; p < e; p += EPI) {
        int pn = p + EPI + grp;
        int cn = 0; float vn = 0.f;
        if (pn < e) { cn = cols[pn]; vn = vals[pn]; }
        float4 h4 = *reinterpret_cast<const float4*>(hw + (long)c * D + sub * 4);
        ax += v * h4.x; ay += v * h4.y; az += v * h4.z; aw += v * h4.w;
        c = cn; v = vn;
    }
#pragma unroll
    for (int m = LPR; m < 64; m <<= 1) {
        ax += __shfl_xor(ax, m, 64);
        ay += __shfl_xor(ay, m, 64);
        az += __shfl_xor(az, m, 64);
        aw += __shfl_xor(aw, m, 64);
    }
    if (grp == 0) {
        float4 o;
        o.x = ax > 0.f ? ax : (__expf(ax) - 1.f);
        o.y = ay > 0.f ? ay : (__expf(ay) - 1.f);
        o.z = az > 0.f ? az : (__expf(az) - 1.f);
        o.w = aw > 0.f ? aw : (__expf(aw) - 1.f);
        *reinterpret_cast<float4*>(out + (long)wave * D + sub * 4) = o;
    }
}

// ---------------- layer-3 SpMM + ELU + fused head GEMM (T = h3 @ S), fp16 out ----
__global__ void spmm_fused3(const int* __restrict__ rowptr, const int* __restrict__ cols,
                            const float* __restrict__ vals, const float* __restrict__ hw,
                            const float* __restrict__ S,
                            short* __restrict__ Hh, short* __restrict__ Th, int n) {
    constexpr int D = 64, LPR = 16, EPI = 4;
    int wave = (blockIdx.x * blockDim.x + threadIdx.x) >> 6;
    int lane = threadIdx.x & 63;
    if (wave >= n) return;
    int sub = lane % LPR, grp = lane / LPR;
    int s = rowptr[wave], e = rowptr[wave + 1];
    float ax = 0.f, ay = 0.f, az = 0.f, aw = 0.f;
    int pe = s + grp;
    int c = 0; float v = 0.f;
    if (pe < e) { c = cols[pe]; v = vals[pe]; }
    for (int p = s; p < e; p += EPI) {
        int pn = p + EPI + grp;
        int cn = 0; float vn = 0.f;
        if (pn < e) { cn = cols[pn]; vn = vals[pn]; }
        float4 h4 = *reinterpret_cast<const float4*>(hw + (long)c * D + sub * 4);
        ax += v * h4.x; ay += v * h4.y; az += v * h4.z; aw += v * h4.w;
        c = cn; v = vn;
    }
#pragma unroll
    for (int m = LPR; m < 64; m <<= 1) {
        ax += __shfl_xor(ax, m, 64);
        ay += __shfl_xor(ay, m, 64);
        az += __shfl_xor(az, m, 64);
        aw += __shfl_xor(aw, m, 64);
    }
    float4 o;
    o.x = ax > 0.f ? ax : (__expf(ax) - 1.f);
    o.y = ay > 0.f ? ay : (__expf(ay) - 1.f);
    o.z = az > 0.f ? az : (__expf(az) - 1.f);
    o.w = aw > 0.f ? aw : (__expf(aw) - 1.f);

    if (grp == 0) {
        short4v hs;
        short t0 = f2h(o.x), t1 = f2h(o.y), t2 = f2h(o.z), t3 = f2h(o.w);
        hs[0] = t0; hs[1] = t1; hs[2] = t2; hs[3] = t3;
        *reinterpret_cast<short4v*>(Hh + (long)wave * D + sub * 4) = hs;
    }

    float t = 0.f;
#pragma unroll
    for (int k = 0; k < 64; k++) {
        float hk;
        switch (k & 3) {
            case 0: hk = __shfl(o.x, k >> 2, 64); break;
            case 1: hk = __shfl(o.y, k >> 2, 64); break;
            case 2: hk = __shfl(o.z, k >> 2, 64); break;
            default: hk = __shfl(o.w, k >> 2, 64); break;
        }
        t += hk * S[k * 64 + lane];
    }
    Th[(long)wave * 64 + lane] = f2h(t);
}

// ---------------- S = (Wb + Wb^T)/2 ----------------
__global__ void sym_kernel(const float* __restrict__ Wb, float* __restrict__ S) {
    int i = blockIdx.x * blockDim.x + threadIdx.x;
    if (i < 64 * 64) {
        int r = i >> 6, c = i & 63;
        S[i] = 0.5f * (Wb[r * 64 + c] + Wb[c * 64 + r]);
    }
}

// ---------------- zero the padded rows of the fp16 operands ----------------
__global__ void pad_zero(short* __restrict__ Th, short* __restrict__ Hh,
                         int startRow, int padRows) {
    int i = blockIdx.x * blockDim.x + threadIdx.x;
    int tot = padRows * 64;
    if (i < tot) {
        long off = (long)startRow * 64 + i;
        Th[off] = 0; Hh[off] = 0;
    }
}

// ---------------- final: out = sigmoid(T @ H^T) via fp16 MFMA ----------------
// R23: single fp16 operand pair (Tl/Hl dropped) -> operand fetch halves (409->205MB)
// and 3 MFMA passes -> 1. Keeps R22's fragment-column interleave (f32x4 nt-stores).
__global__ __launch_bounds__(256, 2) void final_mfma(
    const short* __restrict__ Th, const short* __restrict__ Hh,
    float* __restrict__ out, int n, int G, int ypx) {
    int bid = blockIdx.x;
    int xcd = bid & 7;
    int s4 = bid >> 3;
    int by = xcd * ypx + s4 % ypx;
    int bx = s4 / ypx;
    if (by >= G) return;

    int tid = threadIdx.x;
    int wave = tid >> 6, lane = tid & 63;
    int row0 = by * 128 + (wave >> 1) * 64;
    int col0 = bx * 128 + (wave & 1) * 64;
    int lrow = lane & 15;
    int koff = (lane >> 4) * 8;

    const short* ThB = Th + (long)(row0 + lrow) * 64 + koff;
    // interleaved B: fragment c loads H row col0 + lrow*4 + c
    const short* HhB = Hh + (long)(col0 + lrow * 4) * 64 + koff;

    f32x4 acc[4][4];
#pragma unroll
    for (int r = 0; r < 4; r++)
#pragma unroll
        for (int c = 0; c < 4; c++) acc[r][c] = (f32x4){0.f, 0.f, 0.f, 0.f};

#pragma unroll
    for (int ks = 0; ks < 2; ks++) {
        int kb = ks * 32;
        short8 ah[4];
#pragma unroll
        for (int r = 0; r < 4; r++) ah[r] = *reinterpret_cast<const short8*>(ThB + (long)(r * 16) * 64 + kb);

#pragma unroll
        for (int c = 0; c < 4; c++) {
            short8 bh = *reinterpret_cast<const short8*>(HhB + (long)c * 64 + kb);
#pragma unroll
            for (int r = 0; r < 4; r++)
                acc[r][c] = __builtin_amdgcn_mfma_f32_16x16x32_f16(ah[r], bh, acc[r][c], 0, 0, 0);
        }
    }

    // epilogue: C/D layout col(fragment) = lane&15, row = (lane>>4)*4 + reg;
    // lane's fragment-col m=lrow maps to output cols col0+4*lrow+c.
    int orow = (lane >> 4) * 4;
    bool full = (row0 + 64 <= n) && (col0 + 64 <= n);
    if (full) {
#pragma unroll
        for (int r = 0; r < 4; r++) {
#pragma unroll
            for (int q = 0; q < 4; q++) {
                long base = (long)(row0 + r * 16 + orow + q) * n + col0 + lrow * 4;
                f32x4 v;
                v[0] = __builtin_amdgcn_rcpf(1.f + __expf(-acc[r][0][q]));
                v[1] = __builtin_amdgcn_rcpf(1.f + __expf(-acc[r][1][q]));
                v[2] = __builtin_amdgcn_rcpf(1.f + __expf(-acc[r][2][q]));
                v[3] = __builtin_amdgcn_rcpf(1.f + __expf(-acc[r][3][q]));
                __builtin_nontemporal_store(v, reinterpret_cast<f32x4*>(out + base));
            }
        }
    } else {
#pragma unroll
        for (int r = 0; r < 4; r++) {
#pragma unroll
            for (int q = 0; q < 4; q++) {
                int i = row0 + r * 16 + orow + q;
                if (i < n) {
#pragma unroll
                    for (int c = 0; c < 4; c++) {
                        int j = col0 + lrow * 4 + c;
                        if (j < n) {
                            float x = acc[r][c][q];
                            __builtin_nontemporal_store(__builtin_amdgcn_rcpf(1.f + __expf(-x)),
                                                        out + (long)i * n + j);
                        }
                    }
                }
            }
        }
    }
}

// ---------------- launch ----------------
extern "C" void kernel_launch(void* const* d_in, const int* in_sizes, int n_in,
                              void* d_out, int out_size, void* d_ws, size_t ws_size,
                              hipStream_t stream) {
    const float* x    = (const float*)d_in[0];
    const int*   erow = (const int*)d_in[1];
    const int*   ecol = (const int*)d_in[2];
    const float* eval = (const float*)d_in[3];
    const float* W0   = (const float*)d_in[4];
    const float* W1   = (const float*)d_in[5];
    const float* W2   = (const float*)d_in[6];
    const float* Wb   = (const float*)d_in[7];
    float* out = (float*)d_out;

    int N = in_sizes[0] / 128;
    int E = in_sizes[1];
    int G = (N + 127) / 128;
    int Npad = G * 128;

    char* w = (char*)d_ws;
    size_t off = 0;
    auto alloc = [&](size_t bytes) -> void* {
        void* p = w + off;
        off += (bytes + 255) & ~(size_t)255;
        return p;
    };
    float* bufA    = (float*)alloc((size_t)N * 128 * 4);
    float* bufB    = (float*)alloc((size_t)N * 128 * 4);
    float* S       = (float*)alloc(64 * 64 * 4);
    int*   colsort = (int*)alloc((size_t)E * 4);
    float* valsort = (float*)alloc((size_t)E * 4);
    int*   rowptr  = (int*)alloc((size_t)(N + 1) * 4);
    int*   cursor  = (int*)alloc((size_t)N * 4);
    int*   hist    = (int*)alloc((size_t)N * 4);
    int*   bsum    = (int*)alloc(64 * 4);
    short* Th      = (short*)alloc((size_t)Npad * 64 * 2);
    short* Hh      = (short*)alloc((size_t)Npad * 64 * 2);

    // CSR build (parallel scan)
    int nb = (N + 255) / 256;
    zero_i32<<<(N + 255) / 256, 256, 0, stream>>>(hist, N);
    hist_kernel<<<(E + 255) / 256, 256, 0, stream>>>(erow, hist, E);
    scan_partial<<<nb, 256, 0, stream>>>(hist, bsum, N);
    scan_bsums<<<1, 64, 0, stream>>>(bsum, nb);
    scan_final<<<nb, 256, 0, stream>>>(hist, bsum, rowptr, cursor, N);
    scatter_kernel<<<(E + 255) / 256, 256, 0, stream>>>(erow, ecol, eval, cursor, colsort, valsort, E);

    int gb8 = (N + 7) / 8;
    int spmmG = (N + 3) / 4;
    sym_kernel<<<16, 256, 0, stream>>>(Wb, S);
    // layer 1
    gemm_layer<128, 128><<<gb8, 128, 0, stream>>>(x, W0, bufB, N);
    spmm_elu_v2<128><<<spmmG, 256, 0, stream>>>(rowptr, colsort, valsort, bufB, bufA, N);
    // layer 2
    gemm_layer<128, 128><<<gb8, 128, 0, stream>>>(bufA, W1, bufB, N);
    spmm_elu_v2<128><<<spmmG, 256, 0, stream>>>(rowptr, colsort, valsort, bufB, bufA, N);
    // layer 3 (128 -> 64) + fused head
    gemm_layer<128, 64><<<gb8, 64, 0, stream>>>(bufA, W2, bufB, N);
    spmm_fused3<<<spmmG, 256, 0, stream>>>(rowptr, colsort, valsort, bufB, S, Hh, Th, N);

    int padRows = Npad - N;
    if (padRows > 0)
        pad_zero<<<(padRows * 64 + 255) / 256, 256, 0, stream>>>(Th, Hh, N, padRows);

    int ypx = (G + 7) / 8;                 // y-tiles per XCD band
    int nwg = 8 * ypx * G;                 // padded; blocks with by>=G early-exit
    final_mfma<<<nwg, 256, 0, stream>>>(Th, Hh, out, N, G, ypx);
}

// Round 23
// 265.956 us; speedup vs baseline: 1.5527x; 1.0127x over previous
//
#include <hip/hip_runtime.h>
#include <hip/hip_bf16.h>
#include <hip/hip_fp16.h>
#include <math.h>

typedef short short8 __attribute__((ext_vector_type(8)));
typedef short short4v __attribute__((ext_vector_type(4)));
typedef float f32x4 __attribute__((ext_vector_type(4)));

__device__ inline short f2h(float x) {
    __half h = __float2half(x);
    return *reinterpret_cast<short*>(&h);
}

// ---------------- CSR build ----------------

__global__ void zero_i32(int* __restrict__ p, int n) {
    int i = blockIdx.x * blockDim.x + threadIdx.x;
    if (i < n) p[i] = 0;
}

__global__ void hist_kernel(const int* __restrict__ row, int* __restrict__ hist, int E) {
    int i = blockIdx.x * blockDim.x + threadIdx.x;
    if (i < E) atomicAdd(&hist[row[i]], 1);
}

// ---- parallel scan (bit-identical to serial integer scan) ----
__global__ __launch_bounds__(256) void scan_partial(const int* __restrict__ hist,
                                                    int* __restrict__ bsum, int n) {
    __shared__ int ws_[4];
    int tid = threadIdx.x, lane = tid & 63, wid = tid >> 6;
    int idx = blockIdx.x * 256 + tid;
    int x = (idx < n) ? hist[idx] : 0;
#pragma unroll
    for (int m = 1; m < 64; m <<= 1) x += __shfl_xor(x, m, 64);
    if (lane == 0) ws_[wid] = x;
    __syncthreads();
    if (tid == 0) bsum[blockIdx.x] = ws_[0] + ws_[1] + ws_[2] + ws_[3];
}

// merged: block 0 scans nb (<=64) block sums in place; blocks 1..16 compute
// S = (Wb + Wb^T)/2. Both consumers (scan_final, spmm_fused3) come later.
__global__ __launch_bounds__(256) void scan_bsums_sym(int* __restrict__ bsum, int nb,
                                                      const float* __restrict__ Wb,
                                                      float* __restrict__ S) {
    if (blockIdx.x == 0) {
        int tid = threadIdx.x;
        if (tid < 64) {
            int lane = tid;
            int x = (lane < nb) ? bsum[lane] : 0;
#pragma unroll
            for (int d = 1; d < 64; d <<= 1) {
                int t = __shfl_up(x, d, 64);
                if (lane >= d) x += t;
            }
            if (lane < nb) bsum[lane] = x;
        }
    } else {
        int i = (blockIdx.x - 1) * 256 + threadIdx.x;
        if (i < 64 * 64) {
            int r = i >> 6, c = i & 63;
            S[i] = 0.5f * (Wb[r * 64 + c] + Wb[c * 64 + r]);
        }
    }
}

__global__ __launch_bounds__(256) void scan_final(const int* __restrict__ hist,
                                                  const int* __restrict__ bsum,
                                                  int* __restrict__ rowptr,
                                                  int* __restrict__ cursor, int n) {
    __shared__ int wsum[4];
    int tid = threadIdx.x, lane = tid & 63, wid = tid >> 6;
    int b = blockIdx.x;
    int idx = b * 256 + tid;
    int v = (idx < n) ? hist[idx] : 0;
    int x = v;
#pragma unroll
    for (int d = 1; d < 64; d <<= 1) {
        int t = __shfl_up(x, d, 64);
        if (lane >= d) x += t;
    }
    if (lane == 63) wsum[wid] = x;
    __syncthreads();
    int add = (b > 0) ? bsum[b - 1] : 0;
    for (int w_ = 0; w_ < wid; w_++) add += wsum[w_];
    int inc = x + add;
    if (idx < n) {
        rowptr[idx + 1] = inc;
        cursor[idx] = inc - v;
    }
    if (b == 0 && tid == 0) rowptr[0] = 0;
}

__global__ void scatter_kernel(const int* __restrict__ row, const int* __restrict__ col,
                               const float* __restrict__ val, int* __restrict__ cursor,
                               int* __restrict__ colsort, float* __restrict__ valsort, int E) {
    int i = blockIdx.x * blockDim.x + threadIdx.x;
    if (i < E) {
        int r = row[i];
        int p = atomicAdd(&cursor[r], 1);
        colsort[p] = col[i];
        valsort[p] = val[i];
    }
}

// ---------------- dense layer GEMM: out[n,M] = A[n,K] @ W[K,M] ----------------
template <int K, int M>
__global__ void gemm_layer(const float* __restrict__ A, const float* __restrict__ W,
                           float* __restrict__ out, int n) {
    __shared__ float a[8 * K];
    int j = threadIdx.x;
    int row0 = blockIdx.x * 8;
    constexpr int K4 = K / 4;
    for (int idx = j; idx < 8 * K4; idx += M) {
        int r = idx / K4, k4 = idx % K4;
        float4 v = make_float4(0.f, 0.f, 0.f, 0.f);
        if (row0 + r < n) v = *reinterpret_cast<const float4*>(A + (long)(row0 + r) * K + k4 * 4);
        *reinterpret_cast<float4*>(a + r * K + k4 * 4) = v;
    }
    __syncthreads();
    float acc[8] = {0, 0, 0, 0, 0, 0, 0, 0};
#pragma unroll 8
    for (int k = 0; k < K; k++) {
        float w = W[k * M + j];
#pragma unroll
        for (int r = 0; r < 8; r++) acc[r] += a[r * K + k] * w;
    }
#pragma unroll
    for (int r = 0; r < 8; r++) {
        if (row0 + r < n) out[(long)(row0 + r) * M + j] = acc[r];
    }
}

// ---------------- SpMM v2 full-width ----------------
template <int D>
__global__ void spmm_elu_v2(const int* __restrict__ rowptr, const int* __restrict__ cols,
                            const float* __restrict__ vals, const float* __restrict__ hw,
                            float* __restrict__ out, int n) {
    constexpr int LPR = D / 4;
    constexpr int EPI = 64 / LPR;
    int wave = (blockIdx.x * blockDim.x + threadIdx.x) >> 6;
    int lane = threadIdx.x & 63;
    if (wave >= n) return;
    int sub = lane % LPR, grp = lane / LPR;
    int s = rowptr[wave], e = rowptr[wave + 1];
    float ax = 0.f, ay = 0.f, az = 0.f, aw = 0.f;
    int pe = s + grp;
    int c = 0; float v = 0.f;
    if (pe < e) { c = cols[pe]; v = vals[pe]; }
    for (int p = s; p < e; p += EPI) {
        int pn = p + EPI + grp;
        int cn = 0; float vn = 0.f;
        if (pn < e) { cn = cols[pn]; vn = vals[pn]; }
        float4 h4 = *reinterpret_cast<const float4*>(hw + (long)c * D + sub * 4);
        ax += v * h4.x; ay += v * h4.y; az += v * h4.z; aw += v * h4.w;
        c = cn; v = vn;
    }
#pragma unroll
    for (int m = LPR; m < 64; m <<= 1) {
        ax += __shfl_xor(ax, m, 64);
        ay += __shfl_xor(ay, m, 64);
        az += __shfl_xor(az, m, 64);
        aw += __shfl_xor(aw, m, 64);
    }
    if (grp == 0) {
        float4 o;
        o.x = ax > 0.f ? ax : (__expf(ax) - 1.f);
        o.y = ay > 0.f ? ay : (__expf(ay) - 1.f);
        o.z = az > 0.f ? az : (__expf(az) - 1.f);
        o.w = aw > 0.f ? aw : (__expf(aw) - 1.f);
        *reinterpret_cast<float4*>(out + (long)wave * D + sub * 4) = o;
    }
}

// ---------------- layer-3 SpMM + ELU + fused head GEMM (T = h3 @ S), fp16 out ----
// Grid covers npad rows; pad rows (n..npad) write zero Th/Hh rows (pad_zero folded in).
__global__ void spmm_fused3(const int* __restrict__ rowptr, const int* __restrict__ cols,
                            const float* __restrict__ vals, const float* __restrict__ hw,
                            const float* __restrict__ S,
                            short* __restrict__ Hh, short* __restrict__ Th,
                            int n, int npad) {
    constexpr int D = 64, LPR = 16, EPI = 4;
    int wave = (blockIdx.x * blockDim.x + threadIdx.x) >> 6;
    int lane = threadIdx.x & 63;
    if (wave >= npad) return;
    int sub = lane % LPR, grp = lane / LPR;
    if (wave >= n) {
        // pad row: zero both operand rows
        if (grp == 0) {
            short4v z = {0, 0, 0, 0};
            *reinterpret_cast<short4v*>(Hh + (long)wave * D + sub * 4) = z;
        }
        Th[(long)wave * 64 + lane] = 0;
        return;
    }
    int s = rowptr[wave], e = rowptr[wave + 1];
    float ax = 0.f, ay = 0.f, az = 0.f, aw = 0.f;
    int pe = s + grp;
    int c = 0; float v = 0.f;
    if (pe < e) { c = cols[pe]; v = vals[pe]; }
    for (int p = s; p < e; p += EPI) {
        int pn = p + EPI + grp;
        int cn = 0; float vn = 0.f;
        if (pn < e) { cn = cols[pn]; vn = vals[pn]; }
        float4 h4 = *reinterpret_cast<const float4*>(hw + (long)c * D + sub * 4);
        ax += v * h4.x; ay += v * h4.y; az += v * h4.z; aw += v * h4.w;
        c = cn; v = vn;
    }
#pragma unroll
    for (int m = LPR; m < 64; m <<= 1) {
        ax += __shfl_xor(ax, m, 64);
        ay += __shfl_xor(ay, m, 64);
        az += __shfl_xor(az, m, 64);
        aw += __shfl_xor(aw, m, 64);
    }
    float4 o;
    o.x = ax > 0.f ? ax : (__expf(ax) - 1.f);
    o.y = ay > 0.f ? ay : (__expf(ay) - 1.f);
    o.z = az > 0.f ? az : (__expf(az) - 1.f);
    o.w = aw > 0.f ? aw : (__expf(aw) - 1.f);

    if (grp == 0) {
        short4v hs;
        short t0 = f2h(o.x), t1 = f2h(o.y), t2 = f2h(o.z), t3 = f2h(o.w);
        hs[0] = t0; hs[1] = t1; hs[2] = t2; hs[3] = t3;
        *reinterpret_cast<short4v*>(Hh + (long)wave * D + sub * 4) = hs;
    }

    float t = 0.f;
#pragma unroll
    for (int k = 0; k < 64; k++) {
        float hk;
        switch (k & 3) {
            case 0: hk = __shfl(o.x, k >> 2, 64); break;
            case 1: hk = __shfl(o.y, k >> 2, 64); break;
            case 2: hk = __shfl(o.z, k >> 2, 64); break;
            default: hk = __shfl(o.w, k >> 2, 64); break;
        }
        t += hk * S[k * 64 + lane];
    }
    Th[(long)wave * 64 + lane] = f2h(t);
}

// ---------------- final: out = sigmoid(T @ H^T) via fp16 MFMA ----------------
// fp16 single-pass + fragment-column interleave (f32x4 nt-stores).
__global__ __launch_bounds__(256, 2) void final_mfma(
    const short* __restrict__ Th, const short* __restrict__ Hh,
    float* __restrict__ out, int n, int G, int ypx) {
    int bid = blockIdx.x;
    int xcd = bid & 7;
    int s4 = bid >> 3;
    int by = xcd * ypx + s4 % ypx;
    int bx = s4 / ypx;
    if (by >= G) return;

    int tid = threadIdx.x;
    int wave = tid >> 6, lane = tid & 63;
    int row0 = by * 128 + (wave >> 1) * 64;
    int col0 = bx * 128 + (wave & 1) * 64;
    int lrow = lane & 15;
    int koff = (lane >> 4) * 8;

    const short* ThB = Th + (long)(row0 + lrow) * 64 + koff;
    const short* HhB = Hh + (long)(col0 + lrow * 4) * 64 + koff;

    f32x4 acc[4][4];
#pragma unroll
    for (int r = 0; r < 4; r++)
#pragma unroll
        for (int c = 0; c < 4; c++) acc[r][c] = (f32x4){0.f, 0.f, 0.f, 0.f};

#pragma unroll
    for (int ks = 0; ks < 2; ks++) {
        int kb = ks * 32;
        short8 ah[4];
#pragma unroll
        for (int r = 0; r < 4; r++) ah[r] = *reinterpret_cast<const short8*>(ThB + (long)(r * 16) * 64 + kb);

#pragma unroll
        for (int c = 0; c < 4; c++) {
            short8 bh = *reinterpret_cast<const short8*>(HhB + (long)c * 64 + kb);
#pragma unroll
            for (int r = 0; r < 4; r++)
                acc[r][c] = __builtin_amdgcn_mfma_f32_16x16x32_f16(ah[r], bh, acc[r][c], 0, 0, 0);
        }
    }

    int orow = (lane >> 4) * 4;
    bool full = (row0 + 64 <= n) && (col0 + 64 <= n);
    if (full) {
#pragma unroll
        for (int r = 0; r < 4; r++) {
#pragma unroll
            for (int q = 0; q < 4; q++) {
                long base = (long)(row0 + r * 16 + orow + q) * n + col0 + lrow * 4;
                f32x4 v;
                v[0] = __builtin_amdgcn_rcpf(1.f + __expf(-acc[r][0][q]));
                v[1] = __builtin_amdgcn_rcpf(1.f + __expf(-acc[r][1][q]));
                v[2] = __builtin_amdgcn_rcpf(1.f + __expf(-acc[r][2][q]));
                v[3] = __builtin_amdgcn_rcpf(1.f + __expf(-acc[r][3][q]));
                __builtin_nontemporal_store(v, reinterpret_cast<f32x4*>(out + base));
            }
        }
    } else {
#pragma unroll
        for (int r = 0; r < 4; r++) {
#pragma unroll
            for (int q = 0; q < 4; q++) {
                int i = row0 + r * 16 + orow + q;
                if (i < n) {
#pragma unroll
                    for (int c = 0; c < 4; c++) {
                        int j = col0 + lrow * 4 + c;
                        if (j < n) {
                            float x = acc[r][c][q];
                            __builtin_nontemporal_store(__builtin_amdgcn_rcpf(1.f + __expf(-x)),
                                                        out + (long)i * n + j);
                        }
                    }
                }
            }
        }
    }
}

// ---------------- launch ----------------
extern "C" void kernel_launch(void* const* d_in, const int* in_sizes, int n_in,
                              void* d_out, int out_size, void* d_ws, size_t ws_size,
                              hipStream_t stream) {
    const float* x    = (const float*)d_in[0];
    const int*   erow = (const int*)d_in[1];
    const int*   ecol = (const int*)d_in[2];
    const float* eval = (const float*)d_in[3];
    const float* W0   = (const float*)d_in[4];
    const float* W1   = (const float*)d_in[5];
    const float* W2   = (const float*)d_in[6];
    const float* Wb   = (const float*)d_in[7];
    float* out = (float*)d_out;

    int N = in_sizes[0] / 128;
    int E = in_sizes[1];
    int G = (N + 127) / 128;
    int Npad = G * 128;

    char* w = (char*)d_ws;
    size_t off = 0;
    auto alloc = [&](size_t bytes) -> void* {
        void* p = w + off;
        off += (bytes + 255) & ~(size_t)255;
        return p;
    };
    float* bufA    = (float*)alloc((size_t)N * 128 * 4);
    float* bufB    = (float*)alloc((size_t)N * 128 * 4);
    float* S       = (float*)alloc(64 * 64 * 4);
    int*   colsort = (int*)alloc((size_t)E * 4);
    float* valsort = (float*)alloc((size_t)E * 4);
    int*   rowptr  = (int*)alloc((size_t)(N + 1) * 4);
    int*   cursor  = (int*)alloc((size_t)N * 4);
    int*   hist    = (int*)alloc((size_t)N * 4);
    int*   bsum    = (int*)alloc(64 * 4);
    short* Th      = (short*)alloc((size_t)Npad * 64 * 2);
    short* Hh      = (short*)alloc((size_t)Npad * 64 * 2);

    // CSR build (parallel scan); sym merged into scan_bsums_sym
    int nb = (N + 255) / 256;
    zero_i32<<<(N + 255) / 256, 256, 0, stream>>>(hist, N);
    hist_kernel<<<(E + 255) / 256, 256, 0, stream>>>(erow, hist, E);
    scan_partial<<<nb, 256, 0, stream>>>(hist, bsum, N);
    scan_bsums_sym<<<17, 256, 0, stream>>>(bsum, nb, Wb, S);
    scan_final<<<nb, 256, 0, stream>>>(hist, bsum, rowptr, cursor, N);
    scatter_kernel<<<(E + 255) / 256, 256, 0, stream>>>(erow, ecol, eval, cursor, colsort, valsort, E);

    int gb8 = (N + 7) / 8;
    int spmmG = (N + 3) / 4;
    // layer 1
    gemm_layer<128, 128><<<gb8, 128, 0, stream>>>(x, W0, bufB, N);
    spmm_elu_v2<128><<<spmmG, 256, 0, stream>>>(rowptr, colsort, valsort, bufB, bufA, N);
    // layer 2
    gemm_layer<128, 128><<<gb8, 128, 0, stream>>>(bufA, W1, bufB, N);
    spmm_elu_v2<128><<<spmmG, 256, 0, stream>>>(rowptr, colsort, valsort, bufB, bufA, N);
    // layer 3 (128 -> 64) + fused head + pad-zero folded in (grid covers Npad rows)
    gemm_layer<128, 64><<<gb8, 64, 0, stream>>>(bufA, W2, bufB, N);
    spmm_fused3<<<(Npad + 3) / 4, 256, 0, stream>>>(rowptr, colsort, valsort, bufB, S, Hh, Th, N, Npad);

    int ypx = (G + 7) / 8;                 // y-tiles per XCD band
    int nwg = 8 * ypx * G;                 // padded; blocks with by>=G early-exit
    final_mfma<<<nwg, 256, 0, stream>>>(Th, Hh, out, N, G, ypx);
}